// Round 9
// baseline (714.937 us; speedup 1.0000x reference)
//
#include <hip/hip_runtime.h>
#include <hip/hip_bf16.h>
#include <math.h>

// D_MODEL=1024, D_INNER=2048, NHEADS=32, HEADDIM=64, CHUNK=64, B=4, L=4096
// C == ones collapses the state dim -> scalar scan per (h,p) channel.
//
// R9:
//  - out_proj XCD map fixed: was nb=g&7 -> XCD==nb -> every XCD streamed all
//    64MB of A (FETCH 264MB). Now each XCD owns an M-slice (mb=xcd*8+..):
//    A fetched once, B (4MB) L2-resident.
//  - gemm256x: depth-2 prefetch, 3 LDS buffers (72KB), counted vmcnt(6/3/0)
//    + raw s_barriers. fp16 shrank the K-tile compute window (~160-320cyc)
//    below load latency (~500cyc) -> 1-deep prefetch stalled every tile
//    (MfmaUtil 30%). 2-deep gives 2 iterations of coverage. (R3/R4 counted-
//    vmcnt was null because bf16x3's window ~960cyc already covered latency.)
//  - dtproj2 once for all batches (dtraw_all 2MB in free w2pl slot);
//    u fp16-packed once for all batches (uf_all[b] parked in upper half of
//    yp_all slot b: consumed by in_proj(b), overwritten by passC(b) after).
//
// ws tiers (runtime-checked, deterministic):
//  small  ~100.3 MB : old layout, weights packed per batch, A split in-reg
//  +25.7  ~126.0 MB : weights packed once per call (bf16x3 fallback GEMMs)
//  +16.9  ~142.9 MB : f16 packs -> gemm256x in/out + dtproj path

typedef __attribute__((ext_vector_type(8))) short bf16x8;
typedef __attribute__((ext_vector_type(8))) _Float16 f16x8;
typedef __attribute__((ext_vector_type(4))) float f32x4;

__device__ __forceinline__ float bf2f(unsigned short u) {
    union { float f; unsigned int i; } x; x.i = ((unsigned int)u) << 16; return x.f;
}
__device__ __forceinline__ unsigned short f2bf(float f) {  // RNE
    union { float f; unsigned int i; } x; x.f = f;
    unsigned int r = x.i + 0x7fffu + ((x.i >> 16) & 1u);
    return (unsigned short)(r >> 16);
}
__device__ __forceinline__ unsigned short f2h(float f) {   // fp16 RNE bits
    _Float16 h = (_Float16)f;
    unsigned short u; __builtin_memcpy(&u, &h, 2); return u;
}
__device__ __forceinline__ float h2f(unsigned short u) {
    _Float16 h; __builtin_memcpy(&h, &u, 2); return (float)h;
}
__device__ __forceinline__ float softplusf(float x) {
    return (x > 20.f) ? x : log1pf(expf(x));
}
__device__ __forceinline__ float silu_mod(float x) {  // sigmoid(x)+0.1x per ref
    return 1.f / (1.f + expf(-x)) + 0.1f * x;
}
__device__ __forceinline__ void cvt_split2(float x, float y,
                                           unsigned int* hi, unsigned int* lo) {
    __hip_bfloat162 h2 = __float22bfloat162_rn(make_float2(x, y));
    unsigned int h; __builtin_memcpy(&h, &h2, 4);
    union { float f; unsigned int i; } fx, fy;
    fx.i = h << 16;
    fy.i = h & 0xffff0000u;
    __hip_bfloat162 l2 = __float22bfloat162_rn(make_float2(x - fx.f, y - fy.f));
    unsigned int l; __builtin_memcpy(&l, &l2, 4);
    *hi = h; *lo = l;
}
__device__ __forceinline__ void split4(float4 v, ushort4* h, ushort4* l) {
    unsigned short t;
    t = f2bf(v.x); h->x = t; l->x = f2bf(v.x - bf2f(t));
    t = f2bf(v.y); h->y = t; l->y = f2bf(v.y - bf2f(t));
    t = f2bf(v.z); h->z = t; l->z = f2bf(v.z - bf2f(t));
    t = f2bf(v.w); h->w = t; l->w = f2bf(v.w - bf2f(t));
}

// ---------------------------------------------------------------------------
// pack row-major fp32 -> fragment-order split bf16 (fallback tiers).
// ---------------------------------------------------------------------------
template <int KCN_LOG, int REMAP>
__global__ __launch_bounds__(256) void pack_split(
    const float* __restrict__ src, int src_ld,
    unsigned short* __restrict__ h, unsigned short* __restrict__ l)
{
    int t = blockIdx.x * 256 + threadIdx.x;
    int lane = t & 63;
    int kc = (t >> 6) & ((1 << KCN_LOG) - 1);
    int tile = t >> (6 + KCN_LOG);
    int n = tile * 16 + (lane & 15);
    int k = kc * 32 + (lane >> 4) * 8;
    int sr = n;
    if (REMAP) sr = (n < 4096) ? n : (n < 4128 ? n + 128 : -1);
    float4 v0 = make_float4(0.f, 0.f, 0.f, 0.f), v1 = v0;
    if (sr >= 0) {
        const float* s = src + (size_t)sr * src_ld + k;
        v0 = *(const float4*)s;
        v1 = *(const float4*)(s + 4);
    }
    ushort4 h0, l0, h1, l1;
    split4(v0, &h0, &l0);
    split4(v1, &h1, &l1);
    size_t o = (size_t)t * 8;
    *(ushort4*)(h + o) = h0; *(ushort4*)(h + o + 4) = h1;
    *(ushort4*)(l + o) = l0; *(ushort4*)(l + o + 4) = l1;
}

// ---------------------------------------------------------------------------
// pack_f16: row-major fp32 -> fragment-order fp16 (single copy).
// ---------------------------------------------------------------------------
template <int KCN_LOG>
__global__ __launch_bounds__(256) void pack_f16(
    const float* __restrict__ src, unsigned short* __restrict__ d)
{
    int t = blockIdx.x * 256 + threadIdx.x;
    int lane = t & 63;
    int kc = (t >> 6) & ((1 << KCN_LOG) - 1);
    int tile = t >> (6 + KCN_LOG);
    int n = tile * 16 + (lane & 15);
    int k = kc * 32 + (lane >> 4) * 8;
    const float* s = src + (size_t)n * (32 << KCN_LOG) + k;
    float4 v0 = *(const float4*)s;
    float4 v1 = *(const float4*)(s + 4);
    ushort4 h0, h1;
    h0.x = f2h(v0.x); h0.y = f2h(v0.y); h0.z = f2h(v0.z); h0.w = f2h(v0.w);
    h1.x = f2h(v1.x); h1.y = f2h(v1.y); h1.z = f2h(v1.z); h1.w = f2h(v1.w);
    size_t o = (size_t)t * 8;
    *(ushort4*)(d + o) = h0; *(ushort4*)(d + o + 4) = h1;
}

// ---------------------------------------------------------------------------
// pack_f16_all: all 4 batches of u -> fragment-order fp16, batch b's output
// parked at d + b*8388608 + 4194304 shorts (upper half of yp_all slot b).
// Grid 8192 x 256 (2048 blocks per batch, KCN_LOG=5).
// ---------------------------------------------------------------------------
__global__ __launch_bounds__(256) void pack_f16_all(
    const float* __restrict__ src, unsigned short* __restrict__ d)
{
    int t = blockIdx.x * 256 + threadIdx.x;
    int b = t >> 19;                 // 524288 threads per batch
    int tl = t & 0x7ffff;
    int lane = tl & 63;
    int kc = (tl >> 6) & 31;
    int tile = tl >> 11;
    int n = tile * 16 + (lane & 15);
    int k = kc * 32 + (lane >> 4) * 8;
    const float* s = src + (size_t)b * 4096 * 1024 + (size_t)n * 1024 + k;
    float4 v0 = *(const float4*)s;
    float4 v1 = *(const float4*)(s + 4);
    ushort4 h0, h1;
    h0.x = f2h(v0.x); h0.y = f2h(v0.y); h0.z = f2h(v0.z); h0.w = f2h(v0.w);
    h1.x = f2h(v1.x); h1.y = f2h(v1.y); h1.z = f2h(v1.z); h1.w = f2h(v1.w);
    size_t o = (size_t)b * 8388608 + 4194304 + (size_t)tl * 8;
    *(ushort4*)(d + o) = h0; *(ushort4*)(d + o + 4) = h1;
}

// ---------------------------------------------------------------------------
// pack_dtw: dt weight rows 4224..4255 of in_w -> dtw[k4][h][4] fp32 (128 KB).
// ---------------------------------------------------------------------------
__global__ __launch_bounds__(256) void pack_dtw(
    const float* __restrict__ in_w, float* __restrict__ dtw)
{
    int o = blockIdx.x * 256 + threadIdx.x;   // 32768
    int k4 = o >> 7, rem = o & 127;
    int h = rem >> 2, r = rem & 3;
    dtw[o] = in_w[(size_t)(4224 + h) * 1024 + k4 * 4 + r];
}

// ---------------------------------------------------------------------------
// dtproj2: dtraw[l,h] = dot(u[l,:], dt_w[h,:]) + in_b[4224+h], fp32.
// Launch grid 512 (one batch) or 2048 (all 4 batches, u contiguous).
// ---------------------------------------------------------------------------
__global__ __launch_bounds__(256) void dtproj2(
    const float* __restrict__ u, const float* __restrict__ dtw,
    const float* __restrict__ in_b, float* __restrict__ dtraw)
{
    int idx = blockIdx.x * 256 + threadIdx.x;
    int l = idx >> 5, h = idx & 31;
    const float* ur = u + (size_t)l * 1024;
    const float* wp = dtw + h * 4;
    float s0 = 0.f, s1 = 0.f, s2 = 0.f, s3 = 0.f;
#pragma unroll 4
    for (int k4 = 0; k4 < 256; k4++) {
        float4 a = *(const float4*)(ur + k4 * 4);
        float4 b = *(const float4*)(wp + (size_t)k4 * 128);
        s0 += a.x * b.x; s1 += a.y * b.y;
        s2 += a.z * b.z; s3 += a.w * b.w;
    }
    dtraw[idx] = (s0 + s1) + (s2 + s3) + in_b[4224 + h];
}

// ---------------------------------------------------------------------------
// LDS-free bf16x3 MFMA NT-GEMM (old structure) — kept for fallback tiers.
// ---------------------------------------------------------------------------
template <int ASRC, int OUT, int KDIM, int KSPLIT, int NOFF>
__global__ __launch_bounds__(256, 2) void mfma_gemm(
    const float* __restrict__ Af,
    const unsigned short* __restrict__ Aph, const unsigned short* __restrict__ Apl,
    const unsigned short* __restrict__ Bph, const unsigned short* __restrict__ Bpl,
    const float* __restrict__ bias,
    float* __restrict__ oz, float* __restrict__ oxc,
    float* __restrict__ dtraw, float* __restrict__ outC)
{
    constexpr int KCN = KDIM / 32;       // layout stride (total K chunks)
    constexpr int KCNL = KCN / KSPLIT;   // chunks this block iterates
    const int g = blockIdx.x;
    const int ks = (KSPLIT > 1) ? (g >> 8) : 0;
    const int gg = (KSPLIT > 1) ? (g & 255) : g;
    const int m0 = ((gg & 7) * 4 + ((gg >> 3) & 3)) * 128;
    const int n0 = (gg >> 5) * 128 + NOFF;
    const int tid = threadIdx.x;
    const int lane = tid & 63, w = tid >> 6;
    const int wm = w & 1, wn = w >> 1;
    const int fr = lane & 15, q = lane >> 4;
    const size_t koff = (size_t)ks * KCNL * 512;  // shorts

    const unsigned short* bhp[4];
    const unsigned short* blp[4];
#pragma unroll
    for (int nt = 0; nt < 4; nt++) {
        size_t c = ((size_t)((n0 >> 4) + wn * 4 + nt) * KCN * 64 + lane) * 8 + koff;
        bhp[nt] = Bph + c;
        blp[nt] = Bpl + c;
    }
    const float* afp[4];
    const unsigned short* ahp[4];
    const unsigned short* alp[4];
#pragma unroll
    for (int mt = 0; mt < 4; mt++) {
        if (ASRC == 0) {
            afp[mt] = Af + (size_t)(m0 + wm * 64 + mt * 16 + fr) * KDIM + q * 8
                         + (size_t)ks * (KDIM / KSPLIT);
        } else {
            size_t c = ((size_t)((m0 >> 4) + wm * 4 + mt) * KCN * 64 + lane) * 8 + koff;
            ahp[mt] = Aph + c;
            alp[mt] = Apl + c;
        }
    }

    f32x4 acc[4][4];
#pragma unroll
    for (int i = 0; i < 4; i++)
#pragma unroll
        for (int j = 0; j < 4; j++) acc[i][j] = (f32x4){0.f, 0.f, 0.f, 0.f};

    bf16x8 bh[2][4], bl[2][4], ah[2][4], al[2][4];
    float4 af0[2][4], af1[2][4];

#define LOAD_STEP(B)                                                          \
    {                                                                         \
        _Pragma("unroll") for (int nt = 0; nt < 4; nt++) {                    \
            bh[B][nt] = *(const bf16x8*)bhp[nt];                              \
            bl[B][nt] = *(const bf16x8*)blp[nt];                              \
            bhp[nt] += 512; blp[nt] += 512;                                   \
        }                                                                     \
        _Pragma("unroll") for (int mt = 0; mt < 4; mt++) {                    \
            if (ASRC == 1) {                                                  \
                ah[B][mt] = *(const bf16x8*)ahp[mt];                          \
                al[B][mt] = *(const bf16x8*)alp[mt];                          \
                ahp[mt] += 512; alp[mt] += 512;                               \
            } else {                                                          \
                af0[B][mt] = *(const float4*)afp[mt];                         \
                af1[B][mt] = *(const float4*)(afp[mt] + 4);                   \
                afp[mt] += 32;                                                \
            }                                                                 \
        }                                                                     \
    }

#define MFMA_STEP(B)                                                          \
    {                                                                         \
        bf16x8 xah[4], xal[4];                                                \
        _Pragma("unroll") for (int mt = 0; mt < 4; mt++) {                    \
            if (ASRC == 1) {                                                  \
                xah[mt] = ah[B][mt]; xal[mt] = al[B][mt];                     \
            } else {                                                          \
                union { bf16x8 v; unsigned int u[4]; } H, L;                  \
                cvt_split2(af0[B][mt].x, af0[B][mt].y, &H.u[0], &L.u[0]);     \
                cvt_split2(af0[B][mt].z, af0[B][mt].w, &H.u[1], &L.u[1]);     \
                cvt_split2(af1[B][mt].x, af1[B][mt].y, &H.u[2], &L.u[2]);     \
                cvt_split2(af1[B][mt].z, af1[B][mt].w, &H.u[3], &L.u[3]);     \
                xah[mt] = H.v; xal[mt] = L.v;                                 \
            }                                                                 \
        }                                                                     \
        _Pragma("unroll") for (int mt = 0; mt < 4; mt++)                      \
            _Pragma("unroll") for (int nt = 0; nt < 4; nt++)                  \
                acc[mt][nt] = __builtin_amdgcn_mfma_f32_16x16x32_bf16(        \
                    xah[mt], bh[B][nt], acc[mt][nt], 0, 0, 0);                \
        _Pragma("unroll") for (int mt = 0; mt < 4; mt++)                      \
            _Pragma("unroll") for (int nt = 0; nt < 4; nt++)                  \
                acc[mt][nt] = __builtin_amdgcn_mfma_f32_16x16x32_bf16(        \
                    xah[mt], bl[B][nt], acc[mt][nt], 0, 0, 0);                \
        _Pragma("unroll") for (int mt = 0; mt < 4; mt++)                      \
            _Pragma("unroll") for (int nt = 0; nt < 4; nt++)                  \
                acc[mt][nt] = __builtin_amdgcn_mfma_f32_16x16x32_bf16(        \
                    xal[mt], bh[B][nt], acc[mt][nt], 0, 0, 0);                \
    }

    LOAD_STEP(0);
    for (int kc = 0; kc + 2 < KCNL; kc += 2) {
        LOAD_STEP(1);
        MFMA_STEP(0);
        LOAD_STEP(0);
        MFMA_STEP(1);
    }
    LOAD_STEP(1);
    MFMA_STEP(0);
    MFMA_STEP(1);
#undef LOAD_STEP
#undef MFMA_STEP

    // epilogue: D[row=q*4+reg][col=fr] per 16x16 tile
#pragma unroll
    for (int nt = 0; nt < 4; nt++) {
        int jn = n0 + wn * 64 + nt * 16 + fr;
        if (OUT == 0 && jn >= 4128) continue;
        float bv = 0.f;
        if (OUT == 0) bv = bias[jn < 4096 ? jn : jn + 128];
#pragma unroll
        for (int mt = 0; mt < 4; mt++) {
#pragma unroll
            for (int reg = 0; reg < 4; reg++) {
                int rm = m0 + wm * 64 + mt * 16 + q * 4 + reg;
                float v = acc[mt][nt][reg] + bv;
                if (OUT == 0) {
                    if (jn < 2048)      oz[(size_t)rm * 2048 + jn] = v;
                    else if (jn < 4096) oxc[(size_t)rm * 2048 + (jn - 2048)] = v;
                    else                dtraw[(size_t)rm * 32 + (jn - 4096)] = v;
                } else {
                    float* dst = (KSPLIT == 1 || ks == 0) ? outC : oz;
                    dst[(size_t)rm * 1024 + jn] = v;
                }
            }
        }
    }
}

// ---------------------------------------------------------------------------
// gemm256x: fp16 single-pass 256x128 GEMM, 512 threads (8 waves, 4M x 2N,
// wave tile 64x64), BK=32. Depth-2 prefetch: 3 LDS buffers (72KB, 2
// blocks/CU), counted vmcnt.
//   prologue: STAGE(0) STAGE(1)
//   iter k: [STAGE((k+2)%3), vmcnt(6)] | [vmcnt(3)] | [vmcnt(0)]
//           s_barrier; compute buf[k%3] (16 MFMA); s_barrier
// vmcnt(6): per-wave 3 loads/stage; 6 newer outstanding => stage(k) done.
// Trailing barrier: all reads of buf[k%3] done before iter k+1 stages it.
// OUT 0: in_proj main (N=4096, XCD owns n-slice, +bias -> fp16 z/xc).
// OUT 2: batched out_proj (M=16384, N=1024, K=2048): XCD owns M-slice
//        (mb=xcd*8+..) so A (64MB) is fetched once, B (4MB) L2-resident.
// ---------------------------------------------------------------------------
template <int KCN, int NT, int OUT>
__global__ __launch_bounds__(512, 4) void gemm256x(
    const unsigned short* __restrict__ Ap, const unsigned short* __restrict__ Bp,
    const float* __restrict__ bias,
    unsigned short* __restrict__ ozh, unsigned short* __restrict__ oxch,
    float* __restrict__ outC)
{
    __shared__ unsigned short smem[36864];  // 72 KiB: 3 x (A 8192 + B 4096)
    const int g = blockIdx.x;
    int mb, nb, mbl;
    const unsigned short* Abase = Ap;
    if (OUT == 0) {
        const int xcd = g & 7, loc = g >> 3;  // XCD x owns n-blocks 4x..4x+3
        nb = xcd * 4 + (loc & 3);             // 0..31
        mb = loc >> 2;                        // 0..15
        mbl = mb;
    } else {
        const int xcd = g & 7, loc = g >> 3;
        mb = xcd * 8 + (loc & 7);             // XCD owns M-slice (R9 fix)
        nb = loc >> 3;                        // 0..7
        mbl = mb & 15;                        // row block within batch
        Abase = Ap + (size_t)(mb >> 4) * 4096 * 2048;  // per-batch yp base
    }
    const int tid = threadIdx.x;
    const int lane = tid & 63, w = tid >> 6;
    const int wm = w & 3, wn = w >> 2;        // 4M x 2N
    const int fr = lane & 15, q = lane >> 4;

    // staging: 24 tile-chunks/stage (16 A + 8 B), 3 per wave
    const unsigned short* gp[3];
    int ldso[3];
#pragma unroll
    for (int i = 0; i < 3; i++) {
        const int c = 3 * w + i;
        if (c < 16) {
            gp[i] = Abase + ((size_t)(mbl * 16 + c) * KCN) * 512 + lane * 8;
            ldso[i] = c * 512;
        } else {
            gp[i] = Bp + ((size_t)(nb * 8 + (c - 16)) * KCN) * 512 + lane * 8;
            ldso[i] = 8192 + (c - 16) * 512;
        }
    }

#define STAGE(BUF)                                                            \
    {                                                                         \
        unsigned short* bp = smem + (BUF) * 12288;                            \
        _Pragma("unroll") for (int i = 0; i < 3; i++) {                       \
            __builtin_amdgcn_global_load_lds(                                 \
                (const __attribute__((address_space(1))) unsigned int*)gp[i], \
                (__attribute__((address_space(3))) unsigned int*)(bp + ldso[i]), \
                16, 0, 0);                                                    \
            gp[i] += 512;                                                     \
        }                                                                     \
    }
#define CFENCE asm volatile("" ::: "memory")

    f32x4 acc[4][4];
#pragma unroll
    for (int i = 0; i < 4; i++)
#pragma unroll
        for (int j = 0; j < 4; j++) acc[i][j] = (f32x4){0.f, 0.f, 0.f, 0.f};

    STAGE(0);
    STAGE(1);
    int cb = 0;    // compute buffer
    int sbuf = 2;  // next stage buffer
    for (int kt = 0; kt < NT; ++kt) {
        if (kt + 2 < NT) {
            STAGE(sbuf);
            sbuf = (sbuf == 2) ? 0 : sbuf + 1;
            asm volatile("s_waitcnt vmcnt(6)" ::: "memory");
        } else if (kt + 1 < NT) {
            asm volatile("s_waitcnt vmcnt(3)" ::: "memory");
        } else {
            asm volatile("s_waitcnt vmcnt(0)" ::: "memory");
        }
        __builtin_amdgcn_s_barrier(); CFENCE;
        const unsigned short* sb = smem + cb * 12288;
        cb = (cb == 2) ? 0 : cb + 1;
        f16x8 Bv[4];
#pragma unroll
        for (int nt = 0; nt < 4; nt++)
            Bv[nt] = *(const f16x8*)(sb + 8192 + (wn * 4 + nt) * 512 + lane * 8);
#pragma unroll
        for (int mt = 0; mt < 4; mt++) {
            f16x8 av = *(const f16x8*)(sb + (wm * 4 + mt) * 512 + lane * 8);
            __builtin_amdgcn_s_setprio(1);
#pragma unroll
            for (int nt = 0; nt < 4; nt++)
                acc[mt][nt] = __builtin_amdgcn_mfma_f32_16x16x32_f16(
                    av, Bv[nt], acc[mt][nt], 0, 0, 0);
            __builtin_amdgcn_s_setprio(0);
        }
        __builtin_amdgcn_s_barrier(); CFENCE;
    }
#undef STAGE
#undef CFENCE

    // epilogue: D[row=q*4+reg][col=fr] per 16x16 tile
    const int m0 = mb * 256, n0 = nb * 128;
#pragma unroll
    for (int nt = 0; nt < 4; nt++) {
        const int jn = n0 + wn * 64 + nt * 16 + fr;
        float bv = 0.f;
        if (OUT == 0) bv = bias[jn];
#pragma unroll
        for (int mt = 0; mt < 4; mt++) {
#pragma unroll
            for (int reg = 0; reg < 4; reg++) {
                const int rm = m0 + wm * 64 + mt * 16 + q * 4 + reg;
                float v = acc[mt][nt][reg] + bv;
                if (OUT == 0) {
                    if (jn < 2048) ozh[(size_t)rm * 2048 + jn] = f2h(v);
                    else           oxch[(size_t)rm * 2048 + (jn - 2048)] = f2h(v);
                } else {
                    outC[(size_t)rm * 1024 + jn] = v;
                }
            }
        }
    }
}

// ---------------------------------------------------------------------------
// split-K reduction (fallback tier only).
// ---------------------------------------------------------------------------
__global__ __launch_bounds__(256) void addOut(
    float* __restrict__ dst, const float* __restrict__ part)
{
    size_t i = ((size_t)blockIdx.x * 256 + threadIdx.x) * 4;
    float4 a = *(const float4*)(dst + i);
    float4 b = *(const float4*)(part + i);
    a.x += b.x; a.y += b.y; a.z += b.z; a.w += b.w;
    *(float4*)(dst + i) = a;
}

// ---------------------------------------------------------------------------
// scanA: one batch. Per (h, chunk) block, 64 threads (p). conv4 + silu' +
// softplus(dt) + decay cumsum + 64-step local scan. XT: xc elem type,
// YT: ylocal elem type (fp16 fast tier, fp32 fallback).
// ---------------------------------------------------------------------------
template <typename XT, typename YT>
__global__ __launch_bounds__(64) void scanA(
    const XT* __restrict__ xc,
    const float* __restrict__ dtraw, const float* __restrict__ reward,
    const float* __restrict__ conv_w, const float* __restrict__ conv_b,
    const float* __restrict__ dt_bias, const float* __restrict__ A_log,
    const float* __restrict__ bw, const float* __restrict__ bb,
    YT* __restrict__ ylocal,
    float* __restrict__ decay, float* __restrict__ Fb, float* __restrict__ Eb)
{
    const int blk = blockIdx.x;        // h*64 + t
    const int t = blk & 63;
    const int h = blk >> 6;
    const int p = threadIdx.x;
    const int l0 = t * 64;

    __shared__ float xs[67][65];
    __shared__ float gbuf[64], ebuf[64], dtbuf[64];
    __shared__ float cum63;

    float v1 = bw[p] + bw[p + 64];
    float v2 = bb[p] + bb[p + 64];
#pragma unroll
    for (int o = 32; o > 0; o >>= 1) {
        v1 += __shfl_down(v1, o, 64);
        v2 += __shfl_down(v2, o, 64);
    }
    const float sbw = __shfl(v1, 0, 64);
    const float sbb = __shfl(v2, 0, 64);

    const int l = l0 + p;
    const float dt = softplusf(dtraw[(size_t)l * 32 + h] + dt_bias[h]);
    const float a = -expf(A_log[h]) * dt;
    float cum = a;
#pragma unroll
    for (int o = 1; o < 64; o <<= 1) {
        float uo = __shfl_up(cum, o, 64);
        if (p >= o) cum += uo;
    }
    decay[(size_t)l * 32 + h] = expf(cum);
    gbuf[p] = reward[l] * sbw + sbb;
    ebuf[p] = expf(a);
    dtbuf[p] = dt;
    if (p == 63) cum63 = cum;

    const int c = h * 64 + p;
    for (int r = 0; r < 67; r++) {
        int ls = l0 - 3 + r;
        xs[r][p] = (ls >= 0) ? (float)xc[(size_t)ls * 2048 + c] : 0.f;
    }
    __syncthreads();

    const float w0 = conv_w[c * 4 + 0], w1 = conv_w[c * 4 + 1],
                w2 = conv_w[c * 4 + 2], w3 = conv_w[c * 4 + 3];
    const float cb = conv_b[c];
    float y = 0.f;
    YT* outp = ylocal + (size_t)l0 * 2048 + c;
#pragma unroll 4
    for (int i = 0; i < 64; i++) {
        float v = cb + xs[i][p] * w0 + xs[i + 1][p] * w1 +
                  xs[i + 2][p] * w2 + xs[i + 3][p] * w3;
        float xdt = silu_mod(v) * dtbuf[i];
        y = y * ebuf[i] + gbuf[i] * xdt;
        outp[(size_t)i * 2048] = (YT)y;
    }
    Fb[((size_t)h * 64 + t) * 64 + p] = y;
    if (p == 0) Eb[(size_t)h * 64 + t] = expf(cum63);
}

// ---------------------------------------------------------------------------
// scanB: cross-chunk scan. 32 blocks x 64 threads.
// ---------------------------------------------------------------------------
__global__ __launch_bounds__(64) void scanB(
    const float* __restrict__ Fb, const float* __restrict__ Eb,
    float* __restrict__ Sprev)
{
    int idx = blockIdx.x * blockDim.x + threadIdx.x;  // 2048
    int p = idx & 63;
    int h = idx >> 6;
    int base = h * 64;
    float S = 0.f;
#pragma unroll 8
    for (int t = 0; t < 64; t++) {
        Sprev[(size_t)(base + t) * 64 + p] = S;
        S = S * Eb[base + t] + Fb[(size_t)(base + t) * 64 + p];
    }
}

// ---------------------------------------------------------------------------
// passC: y = (ylocal[fp16] + S*decay) * silu_mod(z[fp16]), emitted as SINGLE
// fp16 in out_proj's A fragment-packed order (KCN=64).
// ---------------------------------------------------------------------------
__global__ __launch_bounds__(256) void passC(
    const unsigned short* __restrict__ ylh, const unsigned short* __restrict__ zh,
    const float* __restrict__ Sprev, const float* __restrict__ decay,
    unsigned short* __restrict__ ypf)
{
    size_t idx = ((size_t)blockIdx.x * 256 + threadIdx.x) * 4;
    int row = (int)(idx >> 11);
    int cc = (int)(idx & 2047);
    int t = row >> 6;
    int h = cc >> 6, p = cc & 63;
    ushort4 av = *(const ushort4*)(ylh + idx);
    ushort4 zv = *(const ushort4*)(zh + idx);
    float4 sv = *(const float4*)(Sprev + ((size_t)(h * 64 + t)) * 64 + p);
    float d = decay[(size_t)row * 32 + h];
    float4 yv;
    yv.x = (h2f(av.x) + sv.x * d) * silu_mod(h2f(zv.x));
    yv.y = (h2f(av.y) + sv.y * d) * silu_mod(h2f(zv.y));
    yv.z = (h2f(av.z) + sv.z * d) * silu_mod(h2f(zv.z));
    yv.w = (h2f(av.w) + sv.w * d) * silu_mod(h2f(zv.w));
    ushort4 hv;
    hv.x = f2h(yv.x); hv.y = f2h(yv.y); hv.z = f2h(yv.z); hv.w = f2h(yv.w);
    size_t chunk = (((size_t)(row >> 4) * 64 + (cc >> 5)) * 64) + ((cc >> 3) & 3) * 16 + (row & 15);
    size_t o = chunk * 8 + (cc & 7);
    *(ushort4*)(ypf + o) = hv;
}

// ---------------------------------------------------------------------------
// passC_bf (fallback tiers): fp32 ylocal/z, split bf16 x2 emit.
// ---------------------------------------------------------------------------
__global__ __launch_bounds__(256) void passC_bf(
    const float* __restrict__ yl, const float* __restrict__ z,
    const float* __restrict__ Sprev, const float* __restrict__ decay,
    unsigned short* __restrict__ yph, unsigned short* __restrict__ ypl)
{
    size_t idx = ((size_t)blockIdx.x * 256 + threadIdx.x) * 4;
    int row = (int)(idx >> 11);
    int cc = (int)(idx & 2047);
    int t = row >> 6;
    int h = cc >> 6, p = cc & 63;
    float4 av = *(const float4*)(yl + idx);
    float4 bvz = *(const float4*)(z + idx);
    float4 sv = *(const float4*)(Sprev + ((size_t)(h * 64 + t)) * 64 + p);
    float d = decay[(size_t)row * 32 + h];
    float4 yv;
    yv.x = (av.x + sv.x * d) * silu_mod(bvz.x);
    yv.y = (av.y + sv.y * d) * silu_mod(bvz.y);
    yv.z = (av.z + sv.z * d) * silu_mod(bvz.z);
    yv.w = (av.w + sv.w * d) * silu_mod(bvz.w);
    ushort4 hv, lv;
    split4(yv, &hv, &lv);
    size_t chunk = (((size_t)(row >> 4) * 64 + (cc >> 5)) * 64) + ((cc >> 3) & 3) * 16 + (row & 15);
    size_t o = chunk * 8 + (cc & 7);
    *(ushort4*)(yph + o) = hv;
    *(ushort4*)(ypl + o) = lv;
}

// ---------------------------------------------------------------------------
extern "C" void kernel_launch(void* const* d_in, const int* in_sizes, int n_in,
                              void* d_out, int out_size, void* d_ws, size_t ws_size,
                              hipStream_t stream)
{
    const float* u       = (const float*)d_in[0];
    const float* reward  = (const float*)d_in[1];
    const float* in_w    = (const float*)d_in[2];
    const float* in_b    = (const float*)d_in[3];
    const float* conv_w  = (const float*)d_in[4];
    const float* conv_b  = (const float*)d_in[5];
    const float* bw      = (const float*)d_in[6];
    const float* bb      = (const float*)d_in[7];
    const float* dt_bias = (const float*)d_in[8];
    const float* A_log   = (const float*)d_in[9];
    const float* out_w   = (const float*)d_in[10];
    float* out = (float*)d_out;

    char* p = (char*)d_ws;
    const size_t SEG = (size_t)4096 * 2048 * 4;  // 33,554,432 B
    // fast tier: R0 = zh (fp16 16MB) + xch (fp16 16MB)
    //            R1+R2 = yp_all (4 x 16MB fp16 fragment-packed); batch b's
    //              fp16 u pack parked in the UPPER 8MB of slot b until
    //              in_proj(b) consumes it (passC(b) then overwrites).
    //            ylocal fp16 (16MB) in the unused w1ph/w1pl slot;
    //            dtraw_all (2MB, 4 batches) in the unused w2pl slot.
    unsigned short* zh  = (unsigned short*)p;
    unsigned short* xch = (unsigned short*)(p + SEG / 2);
    unsigned short* yp_all = (unsigned short*)(p + SEG);
    float* zf = (float*)p;                             // fallback fp32 z  (R0)
    float* xcf = (float*)(p + SEG);                    // fallback fp32 xc (R1)
    unsigned short* yph = (unsigned short*)(p + SEG);  // fallback (R1)
    unsigned short* ypl = yph + (size_t)4096 * 2048;   // fallback (R1+16MB)
    char* R2 = p + 2 * SEG;
    float* ylocal_f = (float*)R2;                      // fallback fp32 ylocal
    char* ps = p + 3 * SEG;                            // tail
    float* dtraw = (float*)ps;                 ps += (size_t)4096 * 32 * 4;
    float* decay = (float*)ps;                 ps += (size_t)4096 * 32 * 4;
    float* Fb    = (float*)ps;                 ps += (size_t)32 * 64 * 64 * 4;
    float* Eb    = (float*)ps;                 ps += (size_t)32 * 64 * 4;
    float* Sprev = (float*)ps;                 ps += (size_t)32 * 64 * 64 * 4;

    const size_t W1PN = (size_t)264 * 32 * 64 * 8;  // shorts per w1 half (bf16 split)
    const size_t W2PN = (size_t)64 * 64 * 64 * 8;   // shorts per w2 half
    const size_t UPN  = (size_t)256 * 32 * 64 * 8;  // shorts: f16-u / f16-w1 slot
    const size_t DTWN = 32768;                      // floats, packed dt weights
    size_t used_small = (size_t)(ps - (char*)d_ws);
    bool wonce = ws_size >= used_small + 2 * sizeof(unsigned short) * (W1PN + W2PN);
    bool upack = ws_size >= used_small + 2 * sizeof(unsigned short) * (W1PN + W2PN + UPN)
                           + sizeof(float) * DTWN;

    unsigned short *w1ph, *w1pl, *w2ph, *w2pl;
    unsigned short *w1f = nullptr, *w2f = nullptr;
    unsigned short *ylh = nullptr;
    float* dtw = nullptr;
    float* dtraw_all = nullptr;
    if (wonce) {
        w1ph = (unsigned short*)ps;
        w1pl = w1ph + W1PN;
        w2ph = w1pl + W1PN;
        w2pl = w2ph + W2PN;
        if (!upack) {
            pack_split<5, 1><<<2112, 256, 0, stream>>>(in_w, 1024, w1ph, w1pl);
            pack_split<6, 0><<<1024, 256, 0, stream>>>(out_w, 2048, w2ph, w2pl);
        } else {
            w2f = w2ph;                   // f16 w2 (single, 4MB) in w2ph slot
            ylh = w1ph;                   // fp16 ylocal (16MB) in w1ph/w1pl slot
            dtraw_all = (float*)w2pl;     // 2MB in free w2pl slot
            unsigned short* uf_slot = w2pl + W2PN;  // (unused now; kept sized)
            w1f = uf_slot + UPN;          // f16 w1 rows 0..4095, 4M shorts
            dtw = (float*)(w1f + UPN);
            pack_f16<6><<<1024, 256, 0, stream>>>(out_w, w2f);
            pack_f16<5><<<2048, 256, 0, stream>>>(in_w, w1f);
            pack_dtw<<<128, 256, 0, stream>>>(in_w, dtw);
            // dt for all 4 batches (u contiguous), fp32
            dtproj2<<<2048, 256, 0, stream>>>(u, dtw, in_b, dtraw_all);
            // u fp16 packs for all 4 batches, parked in yp_all slots
            pack_f16_all<<<8192, 256, 0, stream>>>(u, yp_all);
        }
    } else {
        w1ph = (unsigned short*)R2;
        w1pl = w1ph + W1PN;
        w2ph = (unsigned short*)R2;
        w2pl = w2ph + W2PN;
    }

    for (int b = 0; b < 4; b++) {
        const float* ub = u + (size_t)b * 4096 * 1024;
        const float* rb = reward + (size_t)b * 4096;
        float* ob = out + (size_t)b * 4096 * 1024;

        if (!wonce)
            pack_split<5, 1><<<2112, 256, 0, stream>>>(in_w, 1024, w1ph, w1pl);
        // 1) in_proj
        if (upack) {
            const unsigned short* ufb = yp_all + (size_t)b * 8388608 + 4194304;
            gemm256x<32, 32, 0><<<512, 512, 0, stream>>>(
                ufb, w1f, in_b, zh, xch, nullptr);
        } else {
            mfma_gemm<0, 0, 1024, 1, 0><<<1056, 256, 0, stream>>>(
                ub, nullptr, nullptr, w1ph, w1pl, in_b, zf, xcf, dtraw, nullptr);
        }
        // 2) conv + local chunk scan
        if (upack) {
            scanA<_Float16, _Float16><<<2048, 64, 0, stream>>>(
                (const _Float16*)xch, dtraw_all + (size_t)b * 4096 * 32,
                rb, conv_w, conv_b, dt_bias, A_log, bw, bb,
                (_Float16*)ylh, decay, Fb, Eb);
        } else {
            scanA<float, float><<<2048, 64, 0, stream>>>(
                xcf, dtraw, rb, conv_w, conv_b,
                dt_bias, A_log, bw, bb, ylocal_f, decay, Fb, Eb);
        }
        // 3) cross-chunk scan
        scanB<<<32, 64, 0, stream>>>(Fb, Eb, Sprev);
        // 4) gate + carried state -> yp_all[b] (fast) / yph+ypl (fallback)
        if (upack) {
            passC<<<8192, 256, 0, stream>>>(
                ylh, zh, Sprev, decay, yp_all + (size_t)b * 8388608);
        } else {
            passC_bf<<<8192, 256, 0, stream>>>(ylocal_f, zf, Sprev, decay, yph, ypl);
        }
        if (!upack) {
            if (!wonce)
                pack_split<6, 0><<<1024, 256, 0, stream>>>(out_w, 2048, w2ph, w2pl);
            // fallback out_proj per batch (bf16x3, split-K=2)
            mfma_gemm<1, 1, 2048, 2, 0><<<512, 256, 0, stream>>>(
                nullptr, yph, ypl, w2ph, w2pl, nullptr,
                zf, nullptr, nullptr, ob);
            addOut<<<4096, 256, 0, stream>>>(ob, zf);
        }
    }

    // 5) batched out_proj (fast tier): M=16384, N=1024, K=2048, grid 512 =
    //    2 blocks/CU, XCD owns M-slice, writes d_out directly.
    if (upack) {
        gemm256x<64, 64, 2><<<512, 512, 0, stream>>>(
            yp_all, w2f, nullptr, nullptr, nullptr, out);
    }
}

// Round 10
// 635.741 us; speedup vs baseline: 1.1246x; 1.1246x over previous
//
#include <hip/hip_runtime.h>
#include <hip/hip_bf16.h>
#include <math.h>

// D_MODEL=1024, D_INNER=2048, NHEADS=32, HEADDIM=64, CHUNK=64, B=4, L=4096
// C == ones collapses the state dim -> scalar scan per (h,p) channel.
//
// R10: dtproj2 (grid-2048 fp32 dot kernel) was 149us -- the top dispatch,
// hidden in R4-R8 as 4 sub-cutoff launches. Deleted: dt columns fold back
// into the in_proj fp16 GEMM via REMAP'd w1f pack (264 tiles, N=4224;
// cols 4096..4127 = dt weight rows 4224..4255, 4128..4223 zero). in_proj
// grid 512->528 (blocks 512..527 = dt n-block, R9 map untouched for 0..511);
// epilogue writes dtraw fp32 for jn in [4096,4128). ~+1.5us vs -149us.
// dt error in fp16: ~4e-4 on dtraw -> ~2e-3 on y (within band).
//
// ws tiers (runtime-checked, deterministic):
//  small  ~100.3 MB : old layout, weights packed per batch, A split in-reg
//  +25.7  ~126.0 MB : weights packed once per call (bf16x3 fallback GEMMs)
//  +16.9  ~142.9 MB : f16 packs -> gemm256x in/out path

typedef __attribute__((ext_vector_type(8))) short bf16x8;
typedef __attribute__((ext_vector_type(8))) _Float16 f16x8;
typedef __attribute__((ext_vector_type(4))) float f32x4;

__device__ __forceinline__ float bf2f(unsigned short u) {
    union { float f; unsigned int i; } x; x.i = ((unsigned int)u) << 16; return x.f;
}
__device__ __forceinline__ unsigned short f2bf(float f) {  // RNE
    union { float f; unsigned int i; } x; x.f = f;
    unsigned int r = x.i + 0x7fffu + ((x.i >> 16) & 1u);
    return (unsigned short)(r >> 16);
}
__device__ __forceinline__ unsigned short f2h(float f) {   // fp16 RNE bits
    _Float16 h = (_Float16)f;
    unsigned short u; __builtin_memcpy(&u, &h, 2); return u;
}
__device__ __forceinline__ float h2f(unsigned short u) {
    _Float16 h; __builtin_memcpy(&h, &u, 2); return (float)h;
}
__device__ __forceinline__ float softplusf(float x) {
    return (x > 20.f) ? x : log1pf(expf(x));
}
__device__ __forceinline__ float silu_mod(float x) {  // sigmoid(x)+0.1x per ref
    return 1.f / (1.f + expf(-x)) + 0.1f * x;
}
__device__ __forceinline__ void cvt_split2(float x, float y,
                                           unsigned int* hi, unsigned int* lo) {
    __hip_bfloat162 h2 = __float22bfloat162_rn(make_float2(x, y));
    unsigned int h; __builtin_memcpy(&h, &h2, 4);
    union { float f; unsigned int i; } fx, fy;
    fx.i = h << 16;
    fy.i = h & 0xffff0000u;
    __hip_bfloat162 l2 = __float22bfloat162_rn(make_float2(x - fx.f, y - fy.f));
    unsigned int l; __builtin_memcpy(&l, &l2, 4);
    *hi = h; *lo = l;
}
__device__ __forceinline__ void split4(float4 v, ushort4* h, ushort4* l) {
    unsigned short t;
    t = f2bf(v.x); h->x = t; l->x = f2bf(v.x - bf2f(t));
    t = f2bf(v.y); h->y = t; l->y = f2bf(v.y - bf2f(t));
    t = f2bf(v.z); h->z = t; l->z = f2bf(v.z - bf2f(t));
    t = f2bf(v.w); h->w = t; l->w = f2bf(v.w - bf2f(t));
}

// ---------------------------------------------------------------------------
// pack row-major fp32 -> fragment-order split bf16 (fallback tiers).
// ---------------------------------------------------------------------------
template <int KCN_LOG, int REMAP>
__global__ __launch_bounds__(256) void pack_split(
    const float* __restrict__ src, int src_ld,
    unsigned short* __restrict__ h, unsigned short* __restrict__ l)
{
    int t = blockIdx.x * 256 + threadIdx.x;
    int lane = t & 63;
    int kc = (t >> 6) & ((1 << KCN_LOG) - 1);
    int tile = t >> (6 + KCN_LOG);
    int n = tile * 16 + (lane & 15);
    int k = kc * 32 + (lane >> 4) * 8;
    int sr = n;
    if (REMAP) sr = (n < 4096) ? n : (n < 4128 ? n + 128 : -1);
    float4 v0 = make_float4(0.f, 0.f, 0.f, 0.f), v1 = v0;
    if (sr >= 0) {
        const float* s = src + (size_t)sr * src_ld + k;
        v0 = *(const float4*)s;
        v1 = *(const float4*)(s + 4);
    }
    ushort4 h0, l0, h1, l1;
    split4(v0, &h0, &l0);
    split4(v1, &h1, &l1);
    size_t o = (size_t)t * 8;
    *(ushort4*)(h + o) = h0; *(ushort4*)(h + o + 4) = h1;
    *(ushort4*)(l + o) = l0; *(ushort4*)(l + o + 4) = l1;
}

// ---------------------------------------------------------------------------
// pack_f16: row-major fp32 -> fragment-order fp16 (single copy).
// REMAP (in_w): n<4096 -> row n; 4096..4127 -> row n+128 (dt rows); else 0.
// src_ld = 32<<KCN_LOG.
// ---------------------------------------------------------------------------
template <int KCN_LOG, int REMAP>
__global__ __launch_bounds__(256) void pack_f16(
    const float* __restrict__ src, unsigned short* __restrict__ d)
{
    int t = blockIdx.x * 256 + threadIdx.x;
    int lane = t & 63;
    int kc = (t >> 6) & ((1 << KCN_LOG) - 1);
    int tile = t >> (6 + KCN_LOG);
    int n = tile * 16 + (lane & 15);
    int k = kc * 32 + (lane >> 4) * 8;
    int sr = n;
    if (REMAP) sr = (n < 4096) ? n : (n < 4128 ? n + 128 : -1);
    float4 v0 = make_float4(0.f, 0.f, 0.f, 0.f), v1 = v0;
    if (sr >= 0) {
        const float* s = src + (size_t)sr * (32 << KCN_LOG) + k;
        v0 = *(const float4*)s;
        v1 = *(const float4*)(s + 4);
    }
    ushort4 h0, h1;
    h0.x = f2h(v0.x); h0.y = f2h(v0.y); h0.z = f2h(v0.z); h0.w = f2h(v0.w);
    h1.x = f2h(v1.x); h1.y = f2h(v1.y); h1.z = f2h(v1.z); h1.w = f2h(v1.w);
    size_t o = (size_t)t * 8;
    *(ushort4*)(d + o) = h0; *(ushort4*)(d + o + 4) = h1;
}

// ---------------------------------------------------------------------------
// pack_f16_all: all 4 batches of u -> fragment-order fp16, batch b's output
// parked at d + b*8388608 + 4194304 shorts (upper half of yp_all slot b).
// Grid 8192 x 256 (2048 blocks per batch, KCN_LOG=5).
// ---------------------------------------------------------------------------
__global__ __launch_bounds__(256) void pack_f16_all(
    const float* __restrict__ src, unsigned short* __restrict__ d)
{
    int t = blockIdx.x * 256 + threadIdx.x;
    int b = t >> 19;                 // 524288 threads per batch
    int tl = t & 0x7ffff;
    int lane = tl & 63;
    int kc = (tl >> 6) & 31;
    int tile = tl >> 11;
    int n = tile * 16 + (lane & 15);
    int k = kc * 32 + (lane >> 4) * 8;
    const float* s = src + (size_t)b * 4096 * 1024 + (size_t)n * 1024 + k;
    float4 v0 = *(const float4*)s;
    float4 v1 = *(const float4*)(s + 4);
    ushort4 h0, h1;
    h0.x = f2h(v0.x); h0.y = f2h(v0.y); h0.z = f2h(v0.z); h0.w = f2h(v0.w);
    h1.x = f2h(v1.x); h1.y = f2h(v1.y); h1.z = f2h(v1.z); h1.w = f2h(v1.w);
    size_t o = (size_t)b * 8388608 + 4194304 + (size_t)tl * 8;
    *(ushort4*)(d + o) = h0; *(ushort4*)(d + o + 4) = h1;
}

// ---------------------------------------------------------------------------
// LDS-free bf16x3 MFMA NT-GEMM (old structure) — kept for fallback tiers.
// ---------------------------------------------------------------------------
template <int ASRC, int OUT, int KDIM, int KSPLIT, int NOFF>
__global__ __launch_bounds__(256, 2) void mfma_gemm(
    const float* __restrict__ Af,
    const unsigned short* __restrict__ Aph, const unsigned short* __restrict__ Apl,
    const unsigned short* __restrict__ Bph, const unsigned short* __restrict__ Bpl,
    const float* __restrict__ bias,
    float* __restrict__ oz, float* __restrict__ oxc,
    float* __restrict__ dtraw, float* __restrict__ outC)
{
    constexpr int KCN = KDIM / 32;       // layout stride (total K chunks)
    constexpr int KCNL = KCN / KSPLIT;   // chunks this block iterates
    const int g = blockIdx.x;
    const int ks = (KSPLIT > 1) ? (g >> 8) : 0;
    const int gg = (KSPLIT > 1) ? (g & 255) : g;
    const int m0 = ((gg & 7) * 4 + ((gg >> 3) & 3)) * 128;
    const int n0 = (gg >> 5) * 128 + NOFF;
    const int tid = threadIdx.x;
    const int lane = tid & 63, w = tid >> 6;
    const int wm = w & 1, wn = w >> 1;
    const int fr = lane & 15, q = lane >> 4;
    const size_t koff = (size_t)ks * KCNL * 512;  // shorts

    const unsigned short* bhp[4];
    const unsigned short* blp[4];
#pragma unroll
    for (int nt = 0; nt < 4; nt++) {
        size_t c = ((size_t)((n0 >> 4) + wn * 4 + nt) * KCN * 64 + lane) * 8 + koff;
        bhp[nt] = Bph + c;
        blp[nt] = Bpl + c;
    }
    const float* afp[4];
    const unsigned short* ahp[4];
    const unsigned short* alp[4];
#pragma unroll
    for (int mt = 0; mt < 4; mt++) {
        if (ASRC == 0) {
            afp[mt] = Af + (size_t)(m0 + wm * 64 + mt * 16 + fr) * KDIM + q * 8
                         + (size_t)ks * (KDIM / KSPLIT);
        } else {
            size_t c = ((size_t)((m0 >> 4) + wm * 4 + mt) * KCN * 64 + lane) * 8 + koff;
            ahp[mt] = Aph + c;
            alp[mt] = Apl + c;
        }
    }

    f32x4 acc[4][4];
#pragma unroll
    for (int i = 0; i < 4; i++)
#pragma unroll
        for (int j = 0; j < 4; j++) acc[i][j] = (f32x4){0.f, 0.f, 0.f, 0.f};

    bf16x8 bh[2][4], bl[2][4], ah[2][4], al[2][4];
    float4 af0[2][4], af1[2][4];

#define LOAD_STEP(B)                                                          \
    {                                                                         \
        _Pragma("unroll") for (int nt = 0; nt < 4; nt++) {                    \
            bh[B][nt] = *(const bf16x8*)bhp[nt];                              \
            bl[B][nt] = *(const bf16x8*)blp[nt];                              \
            bhp[nt] += 512; blp[nt] += 512;                                   \
        }                                                                     \
        _Pragma("unroll") for (int mt = 0; mt < 4; mt++) {                    \
            if (ASRC == 1) {                                                  \
                ah[B][mt] = *(const bf16x8*)ahp[mt];                          \
                al[B][mt] = *(const bf16x8*)alp[mt];                          \
                ahp[mt] += 512; alp[mt] += 512;                               \
            } else {                                                          \
                af0[B][mt] = *(const float4*)afp[mt];                         \
                af1[B][mt] = *(const float4*)(afp[mt] + 4);                   \
                afp[mt] += 32;                                                \
            }                                                                 \
        }                                                                     \
    }

#define MFMA_STEP(B)                                                          \
    {                                                                         \
        bf16x8 xah[4], xal[4];                                                \
        _Pragma("unroll") for (int mt = 0; mt < 4; mt++) {                    \
            if (ASRC == 1) {                                                  \
                xah[mt] = ah[B][mt]; xal[mt] = al[B][mt];                     \
            } else {                                                          \
                union { bf16x8 v; unsigned int u[4]; } H, L;                  \
                cvt_split2(af0[B][mt].x, af0[B][mt].y, &H.u[0], &L.u[0]);     \
                cvt_split2(af0[B][mt].z, af0[B][mt].w, &H.u[1], &L.u[1]);     \
                cvt_split2(af1[B][mt].x, af1[B][mt].y, &H.u[2], &L.u[2]);     \
                cvt_split2(af1[B][mt].z, af1[B][mt].w, &H.u[3], &L.u[3]);     \
                xah[mt] = H.v; xal[mt] = L.v;                                 \
            }                                                                 \
        }                                                                     \
        _Pragma("unroll") for (int mt = 0; mt < 4; mt++)                      \
            _Pragma("unroll") for (int nt = 0; nt < 4; nt++)                  \
                acc[mt][nt] = __builtin_amdgcn_mfma_f32_16x16x32_bf16(        \
                    xah[mt], bh[B][nt], acc[mt][nt], 0, 0, 0);                \
        _Pragma("unroll") for (int mt = 0; mt < 4; mt++)                      \
            _Pragma("unroll") for (int nt = 0; nt < 4; nt++)                  \
                acc[mt][nt] = __builtin_amdgcn_mfma_f32_16x16x32_bf16(        \
                    xah[mt], bl[B][nt], acc[mt][nt], 0, 0, 0);                \
        _Pragma("unroll") for (int mt = 0; mt < 4; mt++)                      \
            _Pragma("unroll") for (int nt = 0; nt < 4; nt++)                  \
                acc[mt][nt] = __builtin_amdgcn_mfma_f32_16x16x32_bf16(        \
                    xal[mt], bh[B][nt], acc[mt][nt], 0, 0, 0);                \
    }

    LOAD_STEP(0);
    for (int kc = 0; kc + 2 < KCNL; kc += 2) {
        LOAD_STEP(1);
        MFMA_STEP(0);
        LOAD_STEP(0);
        MFMA_STEP(1);
    }
    LOAD_STEP(1);
    MFMA_STEP(0);
    MFMA_STEP(1);
#undef LOAD_STEP
#undef MFMA_STEP

    // epilogue: D[row=q*4+reg][col=fr] per 16x16 tile
#pragma unroll
    for (int nt = 0; nt < 4; nt++) {
        int jn = n0 + wn * 64 + nt * 16 + fr;
        if (OUT == 0 && jn >= 4128) continue;
        float bv = 0.f;
        if (OUT == 0) bv = bias[jn < 4096 ? jn : jn + 128];
#pragma unroll
        for (int mt = 0; mt < 4; mt++) {
#pragma unroll
            for (int reg = 0; reg < 4; reg++) {
                int rm = m0 + wm * 64 + mt * 16 + q * 4 + reg;
                float v = acc[mt][nt][reg] + bv;
                if (OUT == 0) {
                    if (jn < 2048)      oz[(size_t)rm * 2048 + jn] = v;
                    else if (jn < 4096) oxc[(size_t)rm * 2048 + (jn - 2048)] = v;
                    else                dtraw[(size_t)rm * 32 + (jn - 4096)] = v;
                } else {
                    float* dst = (KSPLIT == 1 || ks == 0) ? outC : oz;
                    dst[(size_t)rm * 1024 + jn] = v;
                }
            }
        }
    }
}

// ---------------------------------------------------------------------------
// gemm256x: fp16 single-pass 256x128 GEMM, 512 threads (8 waves, 4M x 2N,
// wave tile 64x64), BK=32. Depth-2 prefetch: 3 LDS buffers (72KB, 2
// blocks/CU), counted vmcnt(6/3/0) + raw s_barriers.
// OUT 0: in_proj. grid 528: g<512 -> R9 XCD map (xcd owns 4 n-blocks,
//        nb 0..31); g>=512 -> mb=g-512, nb=32 = dt n-block (w1f REMAP
//        pack: cols 4096..4127 = dt rows, 4128..4223 zero). Epilogue:
//        jn<2048 -> fp16 z; <4096 -> fp16 xc; <4128 -> fp32 dtraw; else skip.
// OUT 2: batched out_proj (M=16384, N=1024, K=2048): XCD owns M-slice,
//        A (64MB) fetched once, B (4MB) L2-resident. Writes fp32 out.
// ---------------------------------------------------------------------------
template <int KCN, int NT, int OUT>
__global__ __launch_bounds__(512, 4) void gemm256x(
    const unsigned short* __restrict__ Ap, const unsigned short* __restrict__ Bp,
    const float* __restrict__ bias,
    unsigned short* __restrict__ ozh, unsigned short* __restrict__ oxch,
    float* __restrict__ dtraw, float* __restrict__ outC)
{
    __shared__ unsigned short smem[36864];  // 72 KiB: 3 x (A 8192 + B 4096)
    const int g = blockIdx.x;
    int mb, nb, mbl;
    const unsigned short* Abase = Ap;
    if (OUT == 0) {
        if (g < 512) {
            const int xcd = g & 7, loc = g >> 3;  // XCD x owns n-blocks 4x..4x+3
            nb = xcd * 4 + (loc & 3);             // 0..31
            mb = loc >> 2;                        // 0..15
        } else {
            mb = g - 512;                         // dt n-block
            nb = 32;
        }
        mbl = mb;
    } else {
        const int xcd = g & 7, loc = g >> 3;
        mb = xcd * 8 + (loc & 7);             // XCD owns M-slice
        nb = loc >> 3;                        // 0..7
        mbl = mb & 15;                        // row block within batch
        Abase = Ap + (size_t)(mb >> 4) * 4096 * 2048;  // per-batch yp base
    }
    const int tid = threadIdx.x;
    const int lane = tid & 63, w = tid >> 6;
    const int wm = w & 3, wn = w >> 2;        // 4M x 2N
    const int fr = lane & 15, q = lane >> 4;

    // staging: 24 tile-chunks/stage (16 A + 8 B), 3 per wave
    const unsigned short* gp[3];
    int ldso[3];
#pragma unroll
    for (int i = 0; i < 3; i++) {
        const int c = 3 * w + i;
        if (c < 16) {
            gp[i] = Abase + ((size_t)(mbl * 16 + c) * KCN) * 512 + lane * 8;
            ldso[i] = c * 512;
        } else {
            gp[i] = Bp + ((size_t)(nb * 8 + (c - 16)) * KCN) * 512 + lane * 8;
            ldso[i] = 8192 + (c - 16) * 512;
        }
    }

#define STAGE(BUF)                                                            \
    {                                                                         \
        unsigned short* bp = smem + (BUF) * 12288;                            \
        _Pragma("unroll") for (int i = 0; i < 3; i++) {                       \
            __builtin_amdgcn_global_load_lds(                                 \
                (const __attribute__((address_space(1))) unsigned int*)gp[i], \
                (__attribute__((address_space(3))) unsigned int*)(bp + ldso[i]), \
                16, 0, 0);                                                    \
            gp[i] += 512;                                                     \
        }                                                                     \
    }
#define CFENCE asm volatile("" ::: "memory")

    f32x4 acc[4][4];
#pragma unroll
    for (int i = 0; i < 4; i++)
#pragma unroll
        for (int j = 0; j < 4; j++) acc[i][j] = (f32x4){0.f, 0.f, 0.f, 0.f};

    STAGE(0);
    STAGE(1);
    int cb = 0;    // compute buffer
    int sbuf = 2;  // next stage buffer
    for (int kt = 0; kt < NT; ++kt) {
        if (kt + 2 < NT) {
            STAGE(sbuf);
            sbuf = (sbuf == 2) ? 0 : sbuf + 1;
            asm volatile("s_waitcnt vmcnt(6)" ::: "memory");
        } else if (kt + 1 < NT) {
            asm volatile("s_waitcnt vmcnt(3)" ::: "memory");
        } else {
            asm volatile("s_waitcnt vmcnt(0)" ::: "memory");
        }
        __builtin_amdgcn_s_barrier(); CFENCE;
        const unsigned short* sb = smem + cb * 12288;
        cb = (cb == 2) ? 0 : cb + 1;
        f16x8 Bv[4];
#pragma unroll
        for (int nt = 0; nt < 4; nt++)
            Bv[nt] = *(const f16x8*)(sb + 8192 + (wn * 4 + nt) * 512 + lane * 8);
#pragma unroll
        for (int mt = 0; mt < 4; mt++) {
            f16x8 av = *(const f16x8*)(sb + (wm * 4 + mt) * 512 + lane * 8);
            __builtin_amdgcn_s_setprio(1);
#pragma unroll
            for (int nt = 0; nt < 4; nt++)
                acc[mt][nt] = __builtin_amdgcn_mfma_f32_16x16x32_f16(
                    av, Bv[nt], acc[mt][nt], 0, 0, 0);
            __builtin_amdgcn_s_setprio(0);
        }
        __builtin_amdgcn_s_barrier(); CFENCE;
    }
#undef STAGE
#undef CFENCE

    // epilogue: D[row=q*4+reg][col=fr] per 16x16 tile
    const int m0 = mb * 256, n0 = nb * 128;
#pragma unroll
    for (int nt = 0; nt < 4; nt++) {
        const int jn = n0 + wn * 64 + nt * 16 + fr;
        if (OUT == 0 && jn >= 4128) continue;
        float bv = 0.f;
        if (OUT == 0) bv = bias[jn < 4096 ? jn : jn + 128];
#pragma unroll
        for (int mt = 0; mt < 4; mt++) {
#pragma unroll
            for (int reg = 0; reg < 4; reg++) {
                const int rm = m0 + wm * 64 + mt * 16 + q * 4 + reg;
                float v = acc[mt][nt][reg] + bv;
                if (OUT == 0) {
                    if (jn < 2048)      ozh[(size_t)rm * 2048 + jn] = f2h(v);
                    else if (jn < 4096) oxch[(size_t)rm * 2048 + (jn - 2048)] = f2h(v);
                    else                dtraw[(size_t)rm * 32 + (jn - 4096)] = v;
                } else {
                    outC[(size_t)rm * 1024 + jn] = v;
                }
            }
        }
    }
}

// ---------------------------------------------------------------------------
// split-K reduction (fallback tier only).
// ---------------------------------------------------------------------------
__global__ __launch_bounds__(256) void addOut(
    float* __restrict__ dst, const float* __restrict__ part)
{
    size_t i = ((size_t)blockIdx.x * 256 + threadIdx.x) * 4;
    float4 a = *(const float4*)(dst + i);
    float4 b = *(const float4*)(part + i);
    a.x += b.x; a.y += b.y; a.z += b.z; a.w += b.w;
    *(float4*)(dst + i) = a;
}

// ---------------------------------------------------------------------------
// scanA: one batch. Per (h, chunk) block, 64 threads (p). conv4 + silu' +
// softplus(dt) + decay cumsum + 64-step local scan. XT: xc elem type,
// YT: ylocal elem type (fp16 fast tier, fp32 fallback).
// ---------------------------------------------------------------------------
template <typename XT, typename YT>
__global__ __launch_bounds__(64) void scanA(
    const XT* __restrict__ xc,
    const float* __restrict__ dtraw, const float* __restrict__ reward,
    const float* __restrict__ conv_w, const float* __restrict__ conv_b,
    const float* __restrict__ dt_bias, const float* __restrict__ A_log,
    const float* __restrict__ bw, const float* __restrict__ bb,
    YT* __restrict__ ylocal,
    float* __restrict__ decay, float* __restrict__ Fb, float* __restrict__ Eb)
{
    const int blk = blockIdx.x;        // h*64 + t
    const int t = blk & 63;
    const int h = blk >> 6;
    const int p = threadIdx.x;
    const int l0 = t * 64;

    __shared__ float xs[67][65];
    __shared__ float gbuf[64], ebuf[64], dtbuf[64];
    __shared__ float cum63;

    float v1 = bw[p] + bw[p + 64];
    float v2 = bb[p] + bb[p + 64];
#pragma unroll
    for (int o = 32; o > 0; o >>= 1) {
        v1 += __shfl_down(v1, o, 64);
        v2 += __shfl_down(v2, o, 64);
    }
    const float sbw = __shfl(v1, 0, 64);
    const float sbb = __shfl(v2, 0, 64);

    const int l = l0 + p;
    const float dt = softplusf(dtraw[(size_t)l * 32 + h] + dt_bias[h]);
    const float a = -expf(A_log[h]) * dt;
    float cum = a;
#pragma unroll
    for (int o = 1; o < 64; o <<= 1) {
        float uo = __shfl_up(cum, o, 64);
        if (p >= o) cum += uo;
    }
    decay[(size_t)l * 32 + h] = expf(cum);
    gbuf[p] = reward[l] * sbw + sbb;
    ebuf[p] = expf(a);
    dtbuf[p] = dt;
    if (p == 63) cum63 = cum;

    const int c = h * 64 + p;
    for (int r = 0; r < 67; r++) {
        int ls = l0 - 3 + r;
        xs[r][p] = (ls >= 0) ? (float)xc[(size_t)ls * 2048 + c] : 0.f;
    }
    __syncthreads();

    const float w0 = conv_w[c * 4 + 0], w1 = conv_w[c * 4 + 1],
                w2 = conv_w[c * 4 + 2], w3 = conv_w[c * 4 + 3];
    const float cb = conv_b[c];
    float y = 0.f;
    YT* outp = ylocal + (size_t)l0 * 2048 + c;
#pragma unroll 4
    for (int i = 0; i < 64; i++) {
        float v = cb + xs[i][p] * w0 + xs[i + 1][p] * w1 +
                  xs[i + 2][p] * w2 + xs[i + 3][p] * w3;
        float xdt = silu_mod(v) * dtbuf[i];
        y = y * ebuf[i] + gbuf[i] * xdt;
        outp[(size_t)i * 2048] = (YT)y;
    }
    Fb[((size_t)h * 64 + t) * 64 + p] = y;
    if (p == 0) Eb[(size_t)h * 64 + t] = expf(cum63);
}

// ---------------------------------------------------------------------------
// scanB: cross-chunk scan. 32 blocks x 64 threads.
// ---------------------------------------------------------------------------
__global__ __launch_bounds__(64) void scanB(
    const float* __restrict__ Fb, const float* __restrict__ Eb,
    float* __restrict__ Sprev)
{
    int idx = blockIdx.x * blockDim.x + threadIdx.x;  // 2048
    int p = idx & 63;
    int h = idx >> 6;
    int base = h * 64;
    float S = 0.f;
#pragma unroll 8
    for (int t = 0; t < 64; t++) {
        Sprev[(size_t)(base + t) * 64 + p] = S;
        S = S * Eb[base + t] + Fb[(size_t)(base + t) * 64 + p];
    }
}

// ---------------------------------------------------------------------------
// passC: y = (ylocal[fp16] + S*decay) * silu_mod(z[fp16]), emitted as SINGLE
// fp16 in out_proj's A fragment-packed order (KCN=64).
// ---------------------------------------------------------------------------
__global__ __launch_bounds__(256) void passC(
    const unsigned short* __restrict__ ylh, const unsigned short* __restrict__ zh,
    const float* __restrict__ Sprev, const float* __restrict__ decay,
    unsigned short* __restrict__ ypf)
{
    size_t idx = ((size_t)blockIdx.x * 256 + threadIdx.x) * 4;
    int row = (int)(idx >> 11);
    int cc = (int)(idx & 2047);
    int t = row >> 6;
    int h = cc >> 6, p = cc & 63;
    ushort4 av = *(const ushort4*)(ylh + idx);
    ushort4 zv = *(const ushort4*)(zh + idx);
    float4 sv = *(const float4*)(Sprev + ((size_t)(h * 64 + t)) * 64 + p);
    float d = decay[(size_t)row * 32 + h];
    float4 yv;
    yv.x = (h2f(av.x) + sv.x * d) * silu_mod(h2f(zv.x));
    yv.y = (h2f(av.y) + sv.y * d) * silu_mod(h2f(zv.y));
    yv.z = (h2f(av.z) + sv.z * d) * silu_mod(h2f(zv.z));
    yv.w = (h2f(av.w) + sv.w * d) * silu_mod(h2f(zv.w));
    ushort4 hv;
    hv.x = f2h(yv.x); hv.y = f2h(yv.y); hv.z = f2h(yv.z); hv.w = f2h(yv.w);
    size_t chunk = (((size_t)(row >> 4) * 64 + (cc >> 5)) * 64) + ((cc >> 3) & 3) * 16 + (row & 15);
    size_t o = chunk * 8 + (cc & 7);
    *(ushort4*)(ypf + o) = hv;
}

// ---------------------------------------------------------------------------
// passC_bf (fallback tiers): fp32 ylocal/z, split bf16 x2 emit.
// ---------------------------------------------------------------------------
__global__ __launch_bounds__(256) void passC_bf(
    const float* __restrict__ yl, const float* __restrict__ z,
    const float* __restrict__ Sprev, const float* __restrict__ decay,
    unsigned short* __restrict__ yph, unsigned short* __restrict__ ypl)
{
    size_t idx = ((size_t)blockIdx.x * 256 + threadIdx.x) * 4;
    int row = (int)(idx >> 11);
    int cc = (int)(idx & 2047);
    int t = row >> 6;
    int h = cc >> 6, p = cc & 63;
    float4 av = *(const float4*)(yl + idx);
    float4 bvz = *(const float4*)(z + idx);
    float4 sv = *(const float4*)(Sprev + ((size_t)(h * 64 + t)) * 64 + p);
    float d = decay[(size_t)row * 32 + h];
    float4 yv;
    yv.x = (av.x + sv.x * d) * silu_mod(bvz.x);
    yv.y = (av.y + sv.y * d) * silu_mod(bvz.y);
    yv.z = (av.z + sv.z * d) * silu_mod(bvz.z);
    yv.w = (av.w + sv.w * d) * silu_mod(bvz.w);
    ushort4 hv, lv;
    split4(yv, &hv, &lv);
    size_t chunk = (((size_t)(row >> 4) * 64 + (cc >> 5)) * 64) + ((cc >> 3) & 3) * 16 + (row & 15);
    size_t o = chunk * 8 + (cc & 7);
    *(ushort4*)(yph + o) = hv;
    *(ushort4*)(ypl + o) = lv;
}

// ---------------------------------------------------------------------------
extern "C" void kernel_launch(void* const* d_in, const int* in_sizes, int n_in,
                              void* d_out, int out_size, void* d_ws, size_t ws_size,
                              hipStream_t stream)
{
    const float* u       = (const float*)d_in[0];
    const float* reward  = (const float*)d_in[1];
    const float* in_w    = (const float*)d_in[2];
    const float* in_b    = (const float*)d_in[3];
    const float* conv_w  = (const float*)d_in[4];
    const float* conv_b  = (const float*)d_in[5];
    const float* bw      = (const float*)d_in[6];
    const float* bb      = (const float*)d_in[7];
    const float* dt_bias = (const float*)d_in[8];
    const float* A_log   = (const float*)d_in[9];
    const float* out_w   = (const float*)d_in[10];
    float* out = (float*)d_out;

    char* p = (char*)d_ws;
    const size_t SEG = (size_t)4096 * 2048 * 4;  // 33,554,432 B
    // fast tier: R0 = zh (fp16 16MB) + xch (fp16 16MB)
    //            R1+R2 = yp_all (4 x 16MB fp16 fragment-packed); batch b's
    //              fp16 u pack parked in the UPPER 8MB of slot b until
    //              in_proj(b) consumes it (passC(b) then overwrites).
    //            tail (ps): w2f (4.2MB) + w1f (8.65MB, 264 tiles REMAP) +
    //              ylh (16.8MB) -- fits the unchanged tier reservation.
    unsigned short* zh  = (unsigned short*)p;
    unsigned short* xch = (unsigned short*)(p + SEG / 2);
    unsigned short* yp_all = (unsigned short*)(p + SEG);
    float* zf = (float*)p;                             // fallback fp32 z  (R0)
    float* xcf = (float*)(p + SEG);                    // fallback fp32 xc (R1)
    unsigned short* yph = (unsigned short*)(p + SEG);  // fallback (R1)
    unsigned short* ypl = yph + (size_t)4096 * 2048;   // fallback (R1+16MB)
    char* R2 = p + 2 * SEG;
    float* ylocal_f = (float*)R2;                      // fallback fp32 ylocal
    char* ps = p + 3 * SEG;                            // tail
    float* dtraw = (float*)ps;                 ps += (size_t)4096 * 32 * 4;
    float* decay = (float*)ps;                 ps += (size_t)4096 * 32 * 4;
    float* Fb    = (float*)ps;                 ps += (size_t)32 * 64 * 64 * 4;
    float* Eb    = (float*)ps;                 ps += (size_t)32 * 64 * 4;
    float* Sprev = (float*)ps;                 ps += (size_t)32 * 64 * 64 * 4;

    const size_t W1PN = (size_t)264 * 32 * 64 * 8;  // shorts: w1 half / f16-w1 (264 tiles)
    const size_t W2PN = (size_t)64 * 64 * 64 * 8;   // shorts per w2 half
    const size_t UPN  = (size_t)256 * 32 * 64 * 8;  // shorts (tier sizing)
    const size_t DTWN = 32768;                      // floats (tier sizing)
    size_t used_small = (size_t)(ps - (char*)d_ws);
    bool wonce = ws_size >= used_small + 2 * sizeof(unsigned short) * (W1PN + W2PN);
    bool upack = ws_size >= used_small + 2 * sizeof(unsigned short) * (W1PN + W2PN + UPN)
                           + sizeof(float) * DTWN;

    unsigned short *w1ph, *w1pl, *w2ph, *w2pl;
    unsigned short *w1f = nullptr, *w2f = nullptr;
    unsigned short *ylh = nullptr;
    if (wonce) {
        w1ph = (unsigned short*)ps;
        w1pl = w1ph + W1PN;
        w2ph = w1pl + W1PN;
        w2pl = w2ph + W2PN;
        if (!upack) {
            pack_split<5, 1><<<2112, 256, 0, stream>>>(in_w, 1024, w1ph, w1pl);
            pack_split<6, 0><<<1024, 256, 0, stream>>>(out_w, 2048, w2ph, w2pl);
        } else {
            // fast-tier tail layout: w2f | w1f (264 tiles) | ylh
            w2f = (unsigned short*)ps;
            w1f = w2f + W2PN;
            ylh = w1f + W1PN;
            pack_f16<6, 0><<<1024, 256, 0, stream>>>(out_w, w2f);
            // w1f with REMAP: cols 4096..4127 = dt rows 4224..4255, rest 0
            pack_f16<5, 1><<<2112, 256, 0, stream>>>(in_w, w1f);
            // u fp16 packs for all 4 batches, parked in yp_all slots
            pack_f16_all<<<8192, 256, 0, stream>>>(u, yp_all);
        }
    } else {
        w1ph = (unsigned short*)R2;
        w1pl = w1ph + W1PN;
        w2ph = (unsigned short*)R2;
        w2pl = w2ph + W2PN;
    }

    for (int b = 0; b < 4; b++) {
        const float* ub = u + (size_t)b * 4096 * 1024;
        const float* rb = reward + (size_t)b * 4096;
        float* ob = out + (size_t)b * 4096 * 1024;

        if (!wonce)
            pack_split<5, 1><<<2112, 256, 0, stream>>>(in_w, 1024, w1ph, w1pl);
        // 1) in_proj (dt columns fused: grid 528, blocks 512..527 = nb 32)
        if (upack) {
            const unsigned short* ufb = yp_all + (size_t)b * 8388608 + 4194304;
            gemm256x<32, 32, 0><<<528, 512, 0, stream>>>(
                ufb, w1f, in_b, zh, xch, dtraw, nullptr);
        } else {
            mfma_gemm<0, 0, 1024, 1, 0><<<1056, 256, 0, stream>>>(
                ub, nullptr, nullptr, w1ph, w1pl, in_b, zf, xcf, dtraw, nullptr);
        }
        // 2) conv + local chunk scan
        if (upack) {
            scanA<_Float16, _Float16><<<2048, 64, 0, stream>>>(
                (const _Float16*)xch, dtraw, rb, conv_w, conv_b,
                dt_bias, A_log, bw, bb, (_Float16*)ylh, decay, Fb, Eb);
        } else {
            scanA<float, float><<<2048, 64, 0, stream>>>(
                xcf, dtraw, rb, conv_w, conv_b,
                dt_bias, A_log, bw, bb, ylocal_f, decay, Fb, Eb);
        }
        // 3) cross-chunk scan
        scanB<<<32, 64, 0, stream>>>(Fb, Eb, Sprev);
        // 4) gate + carried state -> yp_all[b] (fast) / yph+ypl (fallback)
        if (upack) {
            passC<<<8192, 256, 0, stream>>>(
                ylh, zh, Sprev, decay, yp_all + (size_t)b * 8388608);
        } else {
            passC_bf<<<8192, 256, 0, stream>>>(ylocal_f, zf, Sprev, decay, yph, ypl);
        }
        if (!upack) {
            if (!wonce)
                pack_split<6, 0><<<1024, 256, 0, stream>>>(out_w, 2048, w2ph, w2pl);
            // fallback out_proj per batch (bf16x3, split-K=2)
            mfma_gemm<1, 1, 2048, 2, 0><<<512, 256, 0, stream>>>(
                nullptr, yph, ypl, w2ph, w2pl, nullptr,
                zf, nullptr, nullptr, ob);
            addOut<<<4096, 256, 0, stream>>>(ob, zf);
        }
    }

    // 5) batched out_proj (fast tier): M=16384, N=1024, K=2048, grid 512 =
    //    2 blocks/CU, XCD owns M-slice, writes d_out directly.
    if (upack) {
        gemm256x<64, 64, 2><<<512, 512, 0, stream>>>(
            yp_all, w2f, nullptr, nullptr, nullptr, nullptr, out);
    }
}

// Round 11
// 588.635 us; speedup vs baseline: 1.2146x; 1.0800x over previous
//
#include <hip/hip_runtime.h>
#include <hip/hip_bf16.h>
#include <math.h>

// D_MODEL=1024, D_INNER=2048, NHEADS=32, HEADDIM=64, CHUNK=64, B=4, L=4096
// C == ones collapses the state dim -> scalar scan per (h,p) channel.
//
// R11: R10's dt fold appended 16 blocks to in_proj's grid (528 > 512 slots
// at 2 blocks/CU) -> the 16 dt blocks ran solo AFTER the wave drained,
// ~+25us per in_proj (hidden just under the top-5 cutoff). Fix: dt as ONE
// batched 64-block GEMM (M=16384 all batches, N=128, K=1024) right after
// pack_f16_all, reading the parked fp16 u packs, writing dtraw_all (2MB).
// in_proj back to grid 512 exactly.
//
// ws tiers (runtime-checked, deterministic):
//  small  ~100.3 MB : old layout, weights packed per batch, A split in-reg
//  +25.7  ~126.0 MB : weights packed once per call (bf16x3 fallback GEMMs)
//  +16.9  ~142.9 MB : f16 packs -> gemm256x in/dt/out path

typedef __attribute__((ext_vector_type(8))) short bf16x8;
typedef __attribute__((ext_vector_type(8))) _Float16 f16x8;
typedef __attribute__((ext_vector_type(4))) float f32x4;

__device__ __forceinline__ float bf2f(unsigned short u) {
    union { float f; unsigned int i; } x; x.i = ((unsigned int)u) << 16; return x.f;
}
__device__ __forceinline__ unsigned short f2bf(float f) {  // RNE
    union { float f; unsigned int i; } x; x.f = f;
    unsigned int r = x.i + 0x7fffu + ((x.i >> 16) & 1u);
    return (unsigned short)(r >> 16);
}
__device__ __forceinline__ unsigned short f2h(float f) {   // fp16 RNE bits
    _Float16 h = (_Float16)f;
    unsigned short u; __builtin_memcpy(&u, &h, 2); return u;
}
__device__ __forceinline__ float h2f(unsigned short u) {
    _Float16 h; __builtin_memcpy(&h, &u, 2); return (float)h;
}
__device__ __forceinline__ float softplusf(float x) {
    return (x > 20.f) ? x : log1pf(expf(x));
}
__device__ __forceinline__ float silu_mod(float x) {  // sigmoid(x)+0.1x per ref
    return 1.f / (1.f + expf(-x)) + 0.1f * x;
}
__device__ __forceinline__ void cvt_split2(float x, float y,
                                           unsigned int* hi, unsigned int* lo) {
    __hip_bfloat162 h2 = __float22bfloat162_rn(make_float2(x, y));
    unsigned int h; __builtin_memcpy(&h, &h2, 4);
    union { float f; unsigned int i; } fx, fy;
    fx.i = h << 16;
    fy.i = h & 0xffff0000u;
    __hip_bfloat162 l2 = __float22bfloat162_rn(make_float2(x - fx.f, y - fy.f));
    unsigned int l; __builtin_memcpy(&l, &l2, 4);
    *hi = h; *lo = l;
}
__device__ __forceinline__ void split4(float4 v, ushort4* h, ushort4* l) {
    unsigned short t;
    t = f2bf(v.x); h->x = t; l->x = f2bf(v.x - bf2f(t));
    t = f2bf(v.y); h->y = t; l->y = f2bf(v.y - bf2f(t));
    t = f2bf(v.z); h->z = t; l->z = f2bf(v.z - bf2f(t));
    t = f2bf(v.w); h->w = t; l->w = f2bf(v.w - bf2f(t));
}

// ---------------------------------------------------------------------------
// pack row-major fp32 -> fragment-order split bf16 (fallback tiers).
// ---------------------------------------------------------------------------
template <int KCN_LOG, int REMAP>
__global__ __launch_bounds__(256) void pack_split(
    const float* __restrict__ src, int src_ld,
    unsigned short* __restrict__ h, unsigned short* __restrict__ l)
{
    int t = blockIdx.x * 256 + threadIdx.x;
    int lane = t & 63;
    int kc = (t >> 6) & ((1 << KCN_LOG) - 1);
    int tile = t >> (6 + KCN_LOG);
    int n = tile * 16 + (lane & 15);
    int k = kc * 32 + (lane >> 4) * 8;
    int sr = n;
    if (REMAP) sr = (n < 4096) ? n : (n < 4128 ? n + 128 : -1);
    float4 v0 = make_float4(0.f, 0.f, 0.f, 0.f), v1 = v0;
    if (sr >= 0) {
        const float* s = src + (size_t)sr * src_ld + k;
        v0 = *(const float4*)s;
        v1 = *(const float4*)(s + 4);
    }
    ushort4 h0, l0, h1, l1;
    split4(v0, &h0, &l0);
    split4(v1, &h1, &l1);
    size_t o = (size_t)t * 8;
    *(ushort4*)(h + o) = h0; *(ushort4*)(h + o + 4) = h1;
    *(ushort4*)(l + o) = l0; *(ushort4*)(l + o + 4) = l1;
}

// ---------------------------------------------------------------------------
// pack_f16: row-major fp32 -> fragment-order fp16 (single copy).
// REMAP (in_w): n<4096 -> row n; 4096..4127 -> row n+128 (dt rows); else 0.
// src_ld = 32<<KCN_LOG.
// ---------------------------------------------------------------------------
template <int KCN_LOG, int REMAP>
__global__ __launch_bounds__(256) void pack_f16(
    const float* __restrict__ src, unsigned short* __restrict__ d)
{
    int t = blockIdx.x * 256 + threadIdx.x;
    int lane = t & 63;
    int kc = (t >> 6) & ((1 << KCN_LOG) - 1);
    int tile = t >> (6 + KCN_LOG);
    int n = tile * 16 + (lane & 15);
    int k = kc * 32 + (lane >> 4) * 8;
    int sr = n;
    if (REMAP) sr = (n < 4096) ? n : (n < 4128 ? n + 128 : -1);
    float4 v0 = make_float4(0.f, 0.f, 0.f, 0.f), v1 = v0;
    if (sr >= 0) {
        const float* s = src + (size_t)sr * (32 << KCN_LOG) + k;
        v0 = *(const float4*)s;
        v1 = *(const float4*)(s + 4);
    }
    ushort4 h0, h1;
    h0.x = f2h(v0.x); h0.y = f2h(v0.y); h0.z = f2h(v0.z); h0.w = f2h(v0.w);
    h1.x = f2h(v1.x); h1.y = f2h(v1.y); h1.z = f2h(v1.z); h1.w = f2h(v1.w);
    size_t o = (size_t)t * 8;
    *(ushort4*)(d + o) = h0; *(ushort4*)(d + o + 4) = h1;
}

// ---------------------------------------------------------------------------
// pack_f16_all: all 4 batches of u -> fragment-order fp16, batch b's output
// parked at d + b*8388608 + 4194304 shorts (upper half of yp_all slot b).
// Grid 8192 x 256 (2048 blocks per batch, KCN_LOG=5).
// ---------------------------------------------------------------------------
__global__ __launch_bounds__(256) void pack_f16_all(
    const float* __restrict__ src, unsigned short* __restrict__ d)
{
    int t = blockIdx.x * 256 + threadIdx.x;
    int b = t >> 19;                 // 524288 threads per batch
    int tl = t & 0x7ffff;
    int lane = tl & 63;
    int kc = (tl >> 6) & 31;
    int tile = tl >> 11;
    int n = tile * 16 + (lane & 15);
    int k = kc * 32 + (lane >> 4) * 8;
    const float* s = src + (size_t)b * 4096 * 1024 + (size_t)n * 1024 + k;
    float4 v0 = *(const float4*)s;
    float4 v1 = *(const float4*)(s + 4);
    ushort4 h0, h1;
    h0.x = f2h(v0.x); h0.y = f2h(v0.y); h0.z = f2h(v0.z); h0.w = f2h(v0.w);
    h1.x = f2h(v1.x); h1.y = f2h(v1.y); h1.z = f2h(v1.z); h1.w = f2h(v1.w);
    size_t o = (size_t)b * 8388608 + 4194304 + (size_t)tl * 8;
    *(ushort4*)(d + o) = h0; *(ushort4*)(d + o + 4) = h1;
}

// ---------------------------------------------------------------------------
// LDS-free bf16x3 MFMA NT-GEMM (old structure) — kept for fallback tiers.
// ---------------------------------------------------------------------------
template <int ASRC, int OUT, int KDIM, int KSPLIT, int NOFF>
__global__ __launch_bounds__(256, 2) void mfma_gemm(
    const float* __restrict__ Af,
    const unsigned short* __restrict__ Aph, const unsigned short* __restrict__ Apl,
    const unsigned short* __restrict__ Bph, const unsigned short* __restrict__ Bpl,
    const float* __restrict__ bias,
    float* __restrict__ oz, float* __restrict__ oxc,
    float* __restrict__ dtraw, float* __restrict__ outC)
{
    constexpr int KCN = KDIM / 32;       // layout stride (total K chunks)
    constexpr int KCNL = KCN / KSPLIT;   // chunks this block iterates
    const int g = blockIdx.x;
    const int ks = (KSPLIT > 1) ? (g >> 8) : 0;
    const int gg = (KSPLIT > 1) ? (g & 255) : g;
    const int m0 = ((gg & 7) * 4 + ((gg >> 3) & 3)) * 128;
    const int n0 = (gg >> 5) * 128 + NOFF;
    const int tid = threadIdx.x;
    const int lane = tid & 63, w = tid >> 6;
    const int wm = w & 1, wn = w >> 1;
    const int fr = lane & 15, q = lane >> 4;
    const size_t koff = (size_t)ks * KCNL * 512;  // shorts

    const unsigned short* bhp[4];
    const unsigned short* blp[4];
#pragma unroll
    for (int nt = 0; nt < 4; nt++) {
        size_t c = ((size_t)((n0 >> 4) + wn * 4 + nt) * KCN * 64 + lane) * 8 + koff;
        bhp[nt] = Bph + c;
        blp[nt] = Bpl + c;
    }
    const float* afp[4];
    const unsigned short* ahp[4];
    const unsigned short* alp[4];
#pragma unroll
    for (int mt = 0; mt < 4; mt++) {
        if (ASRC == 0) {
            afp[mt] = Af + (size_t)(m0 + wm * 64 + mt * 16 + fr) * KDIM + q * 8
                         + (size_t)ks * (KDIM / KSPLIT);
        } else {
            size_t c = ((size_t)((m0 >> 4) + wm * 4 + mt) * KCN * 64 + lane) * 8 + koff;
            ahp[mt] = Aph + c;
            alp[mt] = Apl + c;
        }
    }

    f32x4 acc[4][4];
#pragma unroll
    for (int i = 0; i < 4; i++)
#pragma unroll
        for (int j = 0; j < 4; j++) acc[i][j] = (f32x4){0.f, 0.f, 0.f, 0.f};

    bf16x8 bh[2][4], bl[2][4], ah[2][4], al[2][4];
    float4 af0[2][4], af1[2][4];

#define LOAD_STEP(B)                                                          \
    {                                                                         \
        _Pragma("unroll") for (int nt = 0; nt < 4; nt++) {                    \
            bh[B][nt] = *(const bf16x8*)bhp[nt];                              \
            bl[B][nt] = *(const bf16x8*)blp[nt];                              \
            bhp[nt] += 512; blp[nt] += 512;                                   \
        }                                                                     \
        _Pragma("unroll") for (int mt = 0; mt < 4; mt++) {                    \
            if (ASRC == 1) {                                                  \
                ah[B][mt] = *(const bf16x8*)ahp[mt];                          \
                al[B][mt] = *(const bf16x8*)alp[mt];                          \
                ahp[mt] += 512; alp[mt] += 512;                               \
            } else {                                                          \
                af0[B][mt] = *(const float4*)afp[mt];                         \
                af1[B][mt] = *(const float4*)(afp[mt] + 4);                   \
                afp[mt] += 32;                                                \
            }                                                                 \
        }                                                                     \
    }

#define MFMA_STEP(B)                                                          \
    {                                                                         \
        bf16x8 xah[4], xal[4];                                                \
        _Pragma("unroll") for (int mt = 0; mt < 4; mt++) {                    \
            if (ASRC == 1) {                                                  \
                xah[mt] = ah[B][mt]; xal[mt] = al[B][mt];                     \
            } else {                                                          \
                union { bf16x8 v; unsigned int u[4]; } H, L;                  \
                cvt_split2(af0[B][mt].x, af0[B][mt].y, &H.u[0], &L.u[0]);     \
                cvt_split2(af0[B][mt].z, af0[B][mt].w, &H.u[1], &L.u[1]);     \
                cvt_split2(af1[B][mt].x, af1[B][mt].y, &H.u[2], &L.u[2]);     \
                cvt_split2(af1[B][mt].z, af1[B][mt].w, &H.u[3], &L.u[3]);     \
                xah[mt] = H.v; xal[mt] = L.v;                                 \
            }                                                                 \
        }                                                                     \
        _Pragma("unroll") for (int mt = 0; mt < 4; mt++)                      \
            _Pragma("unroll") for (int nt = 0; nt < 4; nt++)                  \
                acc[mt][nt] = __builtin_amdgcn_mfma_f32_16x16x32_bf16(        \
                    xah[mt], bh[B][nt], acc[mt][nt], 0, 0, 0);                \
        _Pragma("unroll") for (int mt = 0; mt < 4; mt++)                      \
            _Pragma("unroll") for (int nt = 0; nt < 4; nt++)                  \
                acc[mt][nt] = __builtin_amdgcn_mfma_f32_16x16x32_bf16(        \
                    xah[mt], bl[B][nt], acc[mt][nt], 0, 0, 0);                \
        _Pragma("unroll") for (int mt = 0; mt < 4; mt++)                      \
            _Pragma("unroll") for (int nt = 0; nt < 4; nt++)                  \
                acc[mt][nt] = __builtin_amdgcn_mfma_f32_16x16x32_bf16(        \
                    xal[mt], bh[B][nt], acc[mt][nt], 0, 0, 0);                \
    }

    LOAD_STEP(0);
    for (int kc = 0; kc + 2 < KCNL; kc += 2) {
        LOAD_STEP(1);
        MFMA_STEP(0);
        LOAD_STEP(0);
        MFMA_STEP(1);
    }
    LOAD_STEP(1);
    MFMA_STEP(0);
    MFMA_STEP(1);
#undef LOAD_STEP
#undef MFMA_STEP

    // epilogue: D[row=q*4+reg][col=fr] per 16x16 tile
#pragma unroll
    for (int nt = 0; nt < 4; nt++) {
        int jn = n0 + wn * 64 + nt * 16 + fr;
        if (OUT == 0 && jn >= 4128) continue;
        float bv = 0.f;
        if (OUT == 0) bv = bias[jn < 4096 ? jn : jn + 128];
#pragma unroll
        for (int mt = 0; mt < 4; mt++) {
#pragma unroll
            for (int reg = 0; reg < 4; reg++) {
                int rm = m0 + wm * 64 + mt * 16 + q * 4 + reg;
                float v = acc[mt][nt][reg] + bv;
                if (OUT == 0) {
                    if (jn < 2048)      oz[(size_t)rm * 2048 + jn] = v;
                    else if (jn < 4096) oxc[(size_t)rm * 2048 + (jn - 2048)] = v;
                    else                dtraw[(size_t)rm * 32 + (jn - 4096)] = v;
                } else {
                    float* dst = (KSPLIT == 1 || ks == 0) ? outC : oz;
                    dst[(size_t)rm * 1024 + jn] = v;
                }
            }
        }
    }
}

// ---------------------------------------------------------------------------
// gemm256x: fp16 single-pass 256x128 GEMM, 512 threads (8 waves, 4M x 2N,
// wave tile 64x64), BK=32. Depth-2 prefetch: 3 LDS buffers (72KB, 2
// blocks/CU), counted vmcnt(6/3/0) + raw s_barriers.
// OUT 0: in_proj main (grid 512 exactly, R9 XCD map, fp16 z/xc + bias).
// OUT 2: batched out_proj (M=16384, N=1024, K=2048): XCD owns M-slice,
//        A (64MB) fetched once, B (4MB) L2-resident. Writes fp32 out.
// OUT 3: batched dt GEMM (grid 64, ONCE per call): M=16384 (all batches,
//        A = parked fp16 u packs), N=128 (w1f dt tile nb=32, 32 real cols),
//        K=1024. Writes fp32 dtraw_all[rm*32 + (jn-4096)] for jn<4128.
// ---------------------------------------------------------------------------
template <int KCN, int NT, int OUT>
__global__ __launch_bounds__(512, 4) void gemm256x(
    const unsigned short* __restrict__ Ap, const unsigned short* __restrict__ Bp,
    const float* __restrict__ bias,
    unsigned short* __restrict__ ozh, unsigned short* __restrict__ oxch,
    float* __restrict__ dtraw, float* __restrict__ outC)
{
    __shared__ unsigned short smem[36864];  // 72 KiB: 3 x (A 8192 + B 4096)
    const int g = blockIdx.x;
    int mb, nb, mbl;
    const unsigned short* Abase = Ap;
    if (OUT == 0) {
        const int xcd = g & 7, loc = g >> 3;  // XCD x owns n-blocks 4x..4x+3
        nb = xcd * 4 + (loc & 3);             // 0..31
        mb = loc >> 2;                        // 0..15
        mbl = mb;
    } else if (OUT == 2) {
        const int xcd = g & 7, loc = g >> 3;
        mb = xcd * 8 + (loc & 7);             // XCD owns M-slice
        nb = loc >> 3;                        // 0..7
        mbl = mb & 15;                        // row block within batch
        Abase = Ap + (size_t)(mb >> 4) * 8388608;      // per-batch yp base
    } else {                                  // OUT == 3: dt GEMM
        mb = g;                               // 0..63 global row block
        nb = 32;                              // dt tile column of w1f
        mbl = mb & 15;
        Abase = Ap + (size_t)(mb >> 4) * 8388608 + 4194304;  // parked u pack
    }
    const int tid = threadIdx.x;
    const int lane = tid & 63, w = tid >> 6;
    const int wm = w & 3, wn = w >> 2;        // 4M x 2N
    const int fr = lane & 15, q = lane >> 4;

    // staging: 24 tile-chunks/stage (16 A + 8 B), 3 per wave
    const unsigned short* gp[3];
    int ldso[3];
#pragma unroll
    for (int i = 0; i < 3; i++) {
        const int c = 3 * w + i;
        if (c < 16) {
            gp[i] = Abase + ((size_t)(mbl * 16 + c) * KCN) * 512 + lane * 8;
            ldso[i] = c * 512;
        } else {
            gp[i] = Bp + ((size_t)(nb * 8 + (c - 16)) * KCN) * 512 + lane * 8;
            ldso[i] = 8192 + (c - 16) * 512;
        }
    }

#define STAGE(BUF)                                                            \
    {                                                                         \
        unsigned short* bp = smem + (BUF) * 12288;                            \
        _Pragma("unroll") for (int i = 0; i < 3; i++) {                       \
            __builtin_amdgcn_global_load_lds(                                 \
                (const __attribute__((address_space(1))) unsigned int*)gp[i], \
                (__attribute__((address_space(3))) unsigned int*)(bp + ldso[i]), \
                16, 0, 0);                                                    \
            gp[i] += 512;                                                     \
        }                                                                     \
    }
#define CFENCE asm volatile("" ::: "memory")

    f32x4 acc[4][4];
#pragma unroll
    for (int i = 0; i < 4; i++)
#pragma unroll
        for (int j = 0; j < 4; j++) acc[i][j] = (f32x4){0.f, 0.f, 0.f, 0.f};

    STAGE(0);
    STAGE(1);
    int cb = 0;    // compute buffer
    int sbuf = 2;  // next stage buffer
    for (int kt = 0; kt < NT; ++kt) {
        if (kt + 2 < NT) {
            STAGE(sbuf);
            sbuf = (sbuf == 2) ? 0 : sbuf + 1;
            asm volatile("s_waitcnt vmcnt(6)" ::: "memory");
        } else if (kt + 1 < NT) {
            asm volatile("s_waitcnt vmcnt(3)" ::: "memory");
        } else {
            asm volatile("s_waitcnt vmcnt(0)" ::: "memory");
        }
        __builtin_amdgcn_s_barrier(); CFENCE;
        const unsigned short* sb = smem + cb * 12288;
        cb = (cb == 2) ? 0 : cb + 1;
        f16x8 Bv[4];
#pragma unroll
        for (int nt = 0; nt < 4; nt++)
            Bv[nt] = *(const f16x8*)(sb + 8192 + (wn * 4 + nt) * 512 + lane * 8);
#pragma unroll
        for (int mt = 0; mt < 4; mt++) {
            f16x8 av = *(const f16x8*)(sb + (wm * 4 + mt) * 512 + lane * 8);
            __builtin_amdgcn_s_setprio(1);
#pragma unroll
            for (int nt = 0; nt < 4; nt++)
                acc[mt][nt] = __builtin_amdgcn_mfma_f32_16x16x32_f16(
                    av, Bv[nt], acc[mt][nt], 0, 0, 0);
            __builtin_amdgcn_s_setprio(0);
        }
        __builtin_amdgcn_s_barrier(); CFENCE;
    }
#undef STAGE
#undef CFENCE

    // epilogue: D[row=q*4+reg][col=fr] per 16x16 tile
    const int m0 = mb * 256, n0 = nb * 128;
#pragma unroll
    for (int nt = 0; nt < 4; nt++) {
        const int jn = n0 + wn * 64 + nt * 16 + fr;
        if (OUT == 3 && jn >= 4128) continue;
        float bv = 0.f;
        if (OUT == 0) bv = bias[jn];
        if (OUT == 3) bv = bias[jn + 128];   // in_b[4224 + h]
#pragma unroll
        for (int mt = 0; mt < 4; mt++) {
#pragma unroll
            for (int reg = 0; reg < 4; reg++) {
                const int rm = m0 + wm * 64 + mt * 16 + q * 4 + reg;
                float v = acc[mt][nt][reg] + bv;
                if (OUT == 0) {
                    if (jn < 2048) ozh[(size_t)rm * 2048 + jn] = f2h(v);
                    else           oxch[(size_t)rm * 2048 + (jn - 2048)] = f2h(v);
                } else if (OUT == 3) {
                    dtraw[(size_t)rm * 32 + (jn - 4096)] = v;
                } else {
                    outC[(size_t)rm * 1024 + jn] = v;
                }
            }
        }
    }
}

// ---------------------------------------------------------------------------
// split-K reduction (fallback tier only).
// ---------------------------------------------------------------------------
__global__ __launch_bounds__(256) void addOut(
    float* __restrict__ dst, const float* __restrict__ part)
{
    size_t i = ((size_t)blockIdx.x * 256 + threadIdx.x) * 4;
    float4 a = *(const float4*)(dst + i);
    float4 b = *(const float4*)(part + i);
    a.x += b.x; a.y += b.y; a.z += b.z; a.w += b.w;
    *(float4*)(dst + i) = a;
}

// ---------------------------------------------------------------------------
// scanA: one batch. Per (h, chunk) block, 64 threads (p). conv4 + silu' +
// softplus(dt) + decay cumsum + 64-step local scan. XT: xc elem type,
// YT: ylocal elem type (fp16 fast tier, fp32 fallback).
// NOTE: scanA's dt input carries a +dt_bias inside softplus; in the fast
// tier dtraw_all already includes in_b but NOT dt_bias (same as before).
// ---------------------------------------------------------------------------
template <typename XT, typename YT>
__global__ __launch_bounds__(64) void scanA(
    const XT* __restrict__ xc,
    const float* __restrict__ dtraw, const float* __restrict__ reward,
    const float* __restrict__ conv_w, const float* __restrict__ conv_b,
    const float* __restrict__ dt_bias, const float* __restrict__ A_log,
    const float* __restrict__ bw, const float* __restrict__ bb,
    YT* __restrict__ ylocal,
    float* __restrict__ decay, float* __restrict__ Fb, float* __restrict__ Eb)
{
    const int blk = blockIdx.x;        // h*64 + t
    const int t = blk & 63;
    const int h = blk >> 6;
    const int p = threadIdx.x;
    const int l0 = t * 64;

    __shared__ float xs[67][65];
    __shared__ float gbuf[64], ebuf[64], dtbuf[64];
    __shared__ float cum63;

    float v1 = bw[p] + bw[p + 64];
    float v2 = bb[p] + bb[p + 64];
#pragma unroll
    for (int o = 32; o > 0; o >>= 1) {
        v1 += __shfl_down(v1, o, 64);
        v2 += __shfl_down(v2, o, 64);
    }
    const float sbw = __shfl(v1, 0, 64);
    const float sbb = __shfl(v2, 0, 64);

    const int l = l0 + p;
    const float dt = softplusf(dtraw[(size_t)l * 32 + h] + dt_bias[h]);
    const float a = -expf(A_log[h]) * dt;
    float cum = a;
#pragma unroll
    for (int o = 1; o < 64; o <<= 1) {
        float uo = __shfl_up(cum, o, 64);
        if (p >= o) cum += uo;
    }
    decay[(size_t)l * 32 + h] = expf(cum);
    gbuf[p] = reward[l] * sbw + sbb;
    ebuf[p] = expf(a);
    dtbuf[p] = dt;
    if (p == 63) cum63 = cum;

    const int c = h * 64 + p;
    for (int r = 0; r < 67; r++) {
        int ls = l0 - 3 + r;
        xs[r][p] = (ls >= 0) ? (float)xc[(size_t)ls * 2048 + c] : 0.f;
    }
    __syncthreads();

    const float w0 = conv_w[c * 4 + 0], w1 = conv_w[c * 4 + 1],
                w2 = conv_w[c * 4 + 2], w3 = conv_w[c * 4 + 3];
    const float cb = conv_b[c];
    float y = 0.f;
    YT* outp = ylocal + (size_t)l0 * 2048 + c;
#pragma unroll 4
    for (int i = 0; i < 64; i++) {
        float v = cb + xs[i][p] * w0 + xs[i + 1][p] * w1 +
                  xs[i + 2][p] * w2 + xs[i + 3][p] * w3;
        float xdt = silu_mod(v) * dtbuf[i];
        y = y * ebuf[i] + gbuf[i] * xdt;
        outp[(size_t)i * 2048] = (YT)y;
    }
    Fb[((size_t)h * 64 + t) * 64 + p] = y;
    if (p == 0) Eb[(size_t)h * 64 + t] = expf(cum63);
}

// ---------------------------------------------------------------------------
// scanB: cross-chunk scan. 32 blocks x 64 threads.
// ---------------------------------------------------------------------------
__global__ __launch_bounds__(64) void scanB(
    const float* __restrict__ Fb, const float* __restrict__ Eb,
    float* __restrict__ Sprev)
{
    int idx = blockIdx.x * blockDim.x + threadIdx.x;  // 2048
    int p = idx & 63;
    int h = idx >> 6;
    int base = h * 64;
    float S = 0.f;
#pragma unroll 8
    for (int t = 0; t < 64; t++) {
        Sprev[(size_t)(base + t) * 64 + p] = S;
        S = S * Eb[base + t] + Fb[(size_t)(base + t) * 64 + p];
    }
}

// ---------------------------------------------------------------------------
// passC: y = (ylocal[fp16] + S*decay) * silu_mod(z[fp16]), emitted as SINGLE
// fp16 in out_proj's A fragment-packed order (KCN=64).
// ---------------------------------------------------------------------------
__global__ __launch_bounds__(256) void passC(
    const unsigned short* __restrict__ ylh, const unsigned short* __restrict__ zh,
    const float* __restrict__ Sprev, const float* __restrict__ decay,
    unsigned short* __restrict__ ypf)
{
    size_t idx = ((size_t)blockIdx.x * 256 + threadIdx.x) * 4;
    int row = (int)(idx >> 11);
    int cc = (int)(idx & 2047);
    int t = row >> 6;
    int h = cc >> 6, p = cc & 63;
    ushort4 av = *(const ushort4*)(ylh + idx);
    ushort4 zv = *(const ushort4*)(zh + idx);
    float4 sv = *(const float4*)(Sprev + ((size_t)(h * 64 + t)) * 64 + p);
    float d = decay[(size_t)row * 32 + h];
    float4 yv;
    yv.x = (h2f(av.x) + sv.x * d) * silu_mod(h2f(zv.x));
    yv.y = (h2f(av.y) + sv.y * d) * silu_mod(h2f(zv.y));
    yv.z = (h2f(av.z) + sv.z * d) * silu_mod(h2f(zv.z));
    yv.w = (h2f(av.w) + sv.w * d) * silu_mod(h2f(zv.w));
    ushort4 hv;
    hv.x = f2h(yv.x); hv.y = f2h(yv.y); hv.z = f2h(yv.z); hv.w = f2h(yv.w);
    size_t chunk = (((size_t)(row >> 4) * 64 + (cc >> 5)) * 64) + ((cc >> 3) & 3) * 16 + (row & 15);
    size_t o = chunk * 8 + (cc & 7);
    *(ushort4*)(ypf + o) = hv;
}

// ---------------------------------------------------------------------------
// passC_bf (fallback tiers): fp32 ylocal/z, split bf16 x2 emit.
// ---------------------------------------------------------------------------
__global__ __launch_bounds__(256) void passC_bf(
    const float* __restrict__ yl, const float* __restrict__ z,
    const float* __restrict__ Sprev, const float* __restrict__ decay,
    unsigned short* __restrict__ yph, unsigned short* __restrict__ ypl)
{
    size_t idx = ((size_t)blockIdx.x * 256 + threadIdx.x) * 4;
    int row = (int)(idx >> 11);
    int cc = (int)(idx & 2047);
    int t = row >> 6;
    int h = cc >> 6, p = cc & 63;
    float4 av = *(const float4*)(yl + idx);
    float4 bvz = *(const float4*)(z + idx);
    float4 sv = *(const float4*)(Sprev + ((size_t)(h * 64 + t)) * 64 + p);
    float d = decay[(size_t)row * 32 + h];
    float4 yv;
    yv.x = (av.x + sv.x * d) * silu_mod(bvz.x);
    yv.y = (av.y + sv.y * d) * silu_mod(bvz.y);
    yv.z = (av.z + sv.z * d) * silu_mod(bvz.z);
    yv.w = (av.w + sv.w * d) * silu_mod(bvz.w);
    ushort4 hv, lv;
    split4(yv, &hv, &lv);
    size_t chunk = (((size_t)(row >> 4) * 64 + (cc >> 5)) * 64) + ((cc >> 3) & 3) * 16 + (row & 15);
    size_t o = chunk * 8 + (cc & 7);
    *(ushort4*)(yph + o) = hv;
    *(ushort4*)(ypl + o) = lv;
}

// ---------------------------------------------------------------------------
extern "C" void kernel_launch(void* const* d_in, const int* in_sizes, int n_in,
                              void* d_out, int out_size, void* d_ws, size_t ws_size,
                              hipStream_t stream)
{
    const float* u       = (const float*)d_in[0];
    const float* reward  = (const float*)d_in[1];
    const float* in_w    = (const float*)d_in[2];
    const float* in_b    = (const float*)d_in[3];
    const float* conv_w  = (const float*)d_in[4];
    const float* conv_b  = (const float*)d_in[5];
    const float* bw      = (const float*)d_in[6];
    const float* bb      = (const float*)d_in[7];
    const float* dt_bias = (const float*)d_in[8];
    const float* A_log   = (const float*)d_in[9];
    const float* out_w   = (const float*)d_in[10];
    float* out = (float*)d_out;

    char* p = (char*)d_ws;
    const size_t SEG = (size_t)4096 * 2048 * 4;  // 33,554,432 B
    // fast tier: R0 = zh (fp16 16MB) + xch (fp16 16MB)
    //            R1+R2 = yp_all (4 x 16MB fp16 fragment-packed); batch b's
    //              fp16 u pack parked in the UPPER 8MB of slot b until
    //              in_proj(b) consumes it (passC(b) then overwrites).
    //              dt GEMM also reads all parked packs BEFORE the loop.
    //            tail (ps): w2f (4MB) + w1f (8.65MB, 264 tiles REMAP) +
    //              ylh (16.78MB) + dtraw_all (2MB) -- fits reservation.
    unsigned short* zh  = (unsigned short*)p;
    unsigned short* xch = (unsigned short*)(p + SEG / 2);
    unsigned short* yp_all = (unsigned short*)(p + SEG);
    float* zf = (float*)p;                             // fallback fp32 z  (R0)
    float* xcf = (float*)(p + SEG);                    // fallback fp32 xc (R1)
    unsigned short* yph = (unsigned short*)(p + SEG);  // fallback (R1)
    unsigned short* ypl = yph + (size_t)4096 * 2048;   // fallback (R1+16MB)
    char* R2 = p + 2 * SEG;
    float* ylocal_f = (float*)R2;                      // fallback fp32 ylocal
    char* ps = p + 3 * SEG;                            // tail
    float* dtraw = (float*)ps;                 ps += (size_t)4096 * 32 * 4;
    float* decay = (float*)ps;                 ps += (size_t)4096 * 32 * 4;
    float* Fb    = (float*)ps;                 ps += (size_t)32 * 64 * 64 * 4;
    float* Eb    = (float*)ps;                 ps += (size_t)32 * 64 * 4;
    float* Sprev = (float*)ps;                 ps += (size_t)32 * 64 * 64 * 4;

    const size_t W1PN = (size_t)264 * 32 * 64 * 8;  // shorts: w1 half / f16-w1 (264 tiles)
    const size_t W2PN = (size_t)64 * 64 * 64 * 8;   // shorts per w2 half
    const size_t UPN  = (size_t)256 * 32 * 64 * 8;  // shorts (tier sizing)
    const size_t DTWN = 32768;                      // floats (tier sizing)
    size_t used_small = (size_t)(ps - (char*)d_ws);
    bool wonce = ws_size >= used_small + 2 * sizeof(unsigned short) * (W1PN + W2PN);
    bool upack = ws_size >= used_small + 2 * sizeof(unsigned short) * (W1PN + W2PN + UPN)
                           + sizeof(float) * DTWN;

    unsigned short *w1ph, *w1pl, *w2ph, *w2pl;
    unsigned short *w1f = nullptr, *w2f = nullptr;
    unsigned short *ylh = nullptr;
    float* dtraw_all = nullptr;
    if (wonce) {
        w1ph = (unsigned short*)ps;
        w1pl = w1ph + W1PN;
        w2ph = w1pl + W1PN;
        w2pl = w2ph + W2PN;
        if (!upack) {
            pack_split<5, 1><<<2112, 256, 0, stream>>>(in_w, 1024, w1ph, w1pl);
            pack_split<6, 0><<<1024, 256, 0, stream>>>(out_w, 2048, w2ph, w2pl);
        } else {
            // fast-tier tail layout: w2f | w1f (264 tiles) | ylh | dtraw_all
            w2f = (unsigned short*)ps;
            w1f = w2f + W2PN;
            ylh = w1f + W1PN;
            dtraw_all = (float*)(ylh + (size_t)4096 * 2048);
            pack_f16<6, 0><<<1024, 256, 0, stream>>>(out_w, w2f);
            // w1f with REMAP: cols 4096..4127 = dt rows 4224..4255, rest 0
            pack_f16<5, 1><<<2112, 256, 0, stream>>>(in_w, w1f);
            // u fp16 packs for all 4 batches, parked in yp_all slots
            pack_f16_all<<<8192, 256, 0, stream>>>(u, yp_all);
            // batched dt GEMM: M=16384 (all batches), N=128(32 real), K=1024
            gemm256x<32, 32, 3><<<64, 512, 0, stream>>>(
                yp_all, w1f, in_b, nullptr, nullptr, dtraw_all, nullptr);
        }
    } else {
        w1ph = (unsigned short*)R2;
        w1pl = w1ph + W1PN;
        w2ph = (unsigned short*)R2;
        w2pl = w2ph + W2PN;
    }

    for (int b = 0; b < 4; b++) {
        const float* ub = u + (size_t)b * 4096 * 1024;
        const float* rb = reward + (size_t)b * 4096;
        float* ob = out + (size_t)b * 4096 * 1024;

        if (!wonce)
            pack_split<5, 1><<<2112, 256, 0, stream>>>(in_w, 1024, w1ph, w1pl);
        // 1) in_proj (grid 512 exactly = 2 blocks/CU, no tail)
        if (upack) {
            const unsigned short* ufb = yp_all + (size_t)b * 8388608 + 4194304;
            gemm256x<32, 32, 0><<<512, 512, 0, stream>>>(
                ufb, w1f, in_b, zh, xch, nullptr, nullptr);
        } else {
            mfma_gemm<0, 0, 1024, 1, 0><<<1056, 256, 0, stream>>>(
                ub, nullptr, nullptr, w1ph, w1pl, in_b, zf, xcf, dtraw, nullptr);
        }
        // 2) conv + local chunk scan
        if (upack) {
            scanA<_Float16, _Float16><<<2048, 64, 0, stream>>>(
                (const _Float16*)xch, dtraw_all + (size_t)b * 4096 * 32,
                rb, conv_w, conv_b, dt_bias, A_log, bw, bb,
                (_Float16*)ylh, decay, Fb, Eb);
        } else {
            scanA<float, float><<<2048, 64, 0, stream>>>(
                xcf, dtraw, rb, conv_w, conv_b,
                dt_bias, A_log, bw, bb, ylocal_f, decay, Fb, Eb);
        }
        // 3) cross-chunk scan
        scanB<<<32, 64, 0, stream>>>(Fb, Eb, Sprev);
        // 4) gate + carried state -> yp_all[b] (fast) / yph+ypl (fallback)
        if (upack) {
            passC<<<8192, 256, 0, stream>>>(
                ylh, zh, Sprev, decay, yp_all + (size_t)b * 8388608);
        } else {
            passC_bf<<<8192, 256, 0, stream>>>(ylocal_f, zf, Sprev, decay, yph, ypl);
        }
        if (!upack) {
            if (!wonce)
                pack_split<6, 0><<<1024, 256, 0, stream>>>(out_w, 2048, w2ph, w2pl);
            // fallback out_proj per batch (bf16x3, split-K=2)
            mfma_gemm<1, 1, 2048, 2, 0><<<512, 256, 0, stream>>>(
                nullptr, yph, ypl, w2ph, w2pl, nullptr,
                zf, nullptr, nullptr, ob);
            addOut<<<4096, 256, 0, stream>>>(ob, zf);
        }
    }

    // 5) batched out_proj (fast tier): M=16384, N=1024, K=2048, grid 512 =
    //    2 blocks/CU, XCD owns M-slice, writes d_out directly.
    if (upack) {
        gemm256x<64, 64, 2><<<512, 512, 0, stream>>>(
            yp_all, w2f, nullptr, nullptr, nullptr, nullptr, out);
    }
}